// Round 3
// baseline (15200.111 us; speedup 1.0000x reference)
//
#include <hip/hip_runtime.h>
#include <hip/hip_bf16.h>
#include <math.h>

#define HEADS   6
#define DMODEL  1024
#define NPROJ   384
#define DSP     64
#define NPOOL   2048
#define NROWS   8192
#define TILE_M  64
#define KT      64
#define KEEP    16

#define LOG2E_F 1.44269504088896340f
#define LOG2E_D 1.4426950408889634
#define C2      14.4269504088896340f   /* 10*log2(e); |logit| provably < 10 */

typedef __attribute__((ext_vector_type(8))) short short8;
typedef __attribute__((ext_vector_type(4))) float f32x4;

__device__ __forceinline__ bool bet_f(float v, int vi, float w, int wi) {
    return (v > w) || (v == w && vi < wi);
}
__device__ __forceinline__ bool bet_d(double v, int vi, double w, int wi) {
    return (v > w) || (v == w && vi < wi);
}
__device__ __forceinline__ unsigned short f2bf(float f) {   // RNE, no NaN inputs
    unsigned int u = __float_as_uint(f);
    return (unsigned short)((u + 0x7fffu + ((u >> 16) & 1u)) >> 16);
}
__device__ __forceinline__ float bf2f(unsigned short s) {
    return __uint_as_float(((unsigned int)s) << 16);
}
__device__ __forceinline__ unsigned int packbf2(float a, float b) {
    return (unsigned int)f2bf(a) | ((unsigned int)f2bf(b) << 16);
}

// ======================= Kernel 1: fp64 projection =======================
// h (64 rows x 64 cols per block) written into the block's own output region:
//   h_hi f32 [64][64] at out+obase, h_lo bf16 [64][64] at out+obase+4096 floats.
__global__ __launch_bounds__(256, 4)
void proj_k(const float* __restrict__ x, const float* __restrict__ Wm,
            const float* __restrict__ bb, float* __restrict__ out)
{
    __shared__ __align__(16) float stage[64*68];  // x tile, [k][row]

    const int t    = threadIdx.x;
    const int cg   = t & 15;
    const int rg   = t >> 4;
    const int head = blockIdx.y;
    const int row0 = blockIdx.x * TILE_M;
    const size_t obase = ((size_t)head*NROWS + row0) * (size_t)NPOOL;

    double acc0[4][4];
    #pragma unroll
    for (int i=0;i<4;i++) {
        #pragma unroll
        for (int j=0;j<4;j++) acc0[i][j] = 0.0;
    }
    const int xr = t >> 2;
    const int xq = t & 3;
    const float* wcol = Wm + head*64 + cg*4;

    for (int kk = 0; kk < DMODEL; kk += KT) {
        const float* xsrc = x + (size_t)(row0+xr)*DMODEL + kk + xq*16;
        float4 xv[4];
        #pragma unroll
        for (int q=0;q<4;q++) xv[q] = *(const float4*)(xsrc + q*4);
        __syncthreads();
        #pragma unroll
        for (int q=0;q<4;q++) {
            const int k = xq*16 + q*4;
            stage[(k+0)*68 + xr] = xv[q].x;
            stage[(k+1)*68 + xr] = xv[q].y;
            stage[(k+2)*68 + xr] = xv[q].z;
            stage[(k+3)*68 + xr] = xv[q].w;
        }
        __syncthreads();
        const float* wk = wcol + (size_t)kk*NPROJ;
        #pragma unroll 4
        for (int k=0;k<KT;k++) {
            const float4 xf = *(const float4*)&stage[k*68 + rg*4];
            const float4 wf = *(const float4*)(wk + (size_t)k*NPROJ);
            const double xd[4] = {(double)xf.x,(double)xf.y,(double)xf.z,(double)xf.w};
            const double wd[4] = {(double)wf.x,(double)wf.y,(double)wf.z,(double)wf.w};
            #pragma unroll
            for (int i=0;i<4;i++) {
                #pragma unroll
                for (int j=0;j<4;j++)
                    acc0[i][j] = fma(xd[i], wd[j], acc0[i][j]);
            }
        }
    }

    float*  hhi = out + obase;                       // [64][64] f32
    ushort* hlo = (ushort*)(out + obase + 4096);     // [64][64] bf16
    #pragma unroll
    for (int i=0;i<4;i++) {
        float4  hv; ushort4 lv;
        double vv[4];
        #pragma unroll
        for (int j=0;j<4;j++) vv[j] = acc0[i][j] + (double)bb[head*64 + cg*4 + j];
        hv.x=(float)vv[0]; hv.y=(float)vv[1]; hv.z=(float)vv[2]; hv.w=(float)vv[3];
        lv.x=f2bf((float)(vv[0]-(double)hv.x)); lv.y=f2bf((float)(vv[1]-(double)hv.y));
        lv.z=f2bf((float)(vv[2]-(double)hv.z)); lv.w=f2bf((float)(vv[3]-(double)hv.w));
        *(float4*) &hhi[(size_t)(rg*4+i)*64 + cg*4] = hv;
        *(ushort4*)&hlo[(size_t)(rg*4+i)*64 + cg*4] = lv;
    }
}

// ======================= Kernel 2: router =======================
__global__ __launch_bounds__(256, 4)
void route_k(const float* __restrict__ emb, float* __restrict__ out)
{
    __shared__ __align__(16) double smem_d[2560];   // 20480 B multi-use
    __shared__ int   ridx16[64*16];                 // 4096 B
    __shared__ float zbuf[64];
    short*  e_bf   = (short*)smem_d;                // [128][68] bf16 (phase 1)
    float*  cand   = (float*)smem_d;                // [256][18] (merge)
    double* rv     = smem_d;                        // [64][17]  (rescore)
    float*  final8 = ((float*)smem_d) + 2304;       // [64][16]  (byte 9216+)

    const int t    = threadIdx.x;
    const int lane = t & 63, wv = t >> 6;
    const int m    = lane & 15, q = lane >> 4;
    const int head = blockIdx.y;
    const int row0 = blockIdx.x * TILE_M;
    const size_t obase = ((size_t)head*NROWS + row0) * (size_t)NPOOL;

    int psel = 0;                 // pools: [fqk,fqk,fv,rqk,rqk,rv]
    if (head >= 2) psel = 1;
    if (head >= 3) psel = 2;
    if (head >= 5) psel = 3;
    const float* epool = emb + (size_t)psel * NPOOL * DSP;

    // ---- A fragments: h rows of this wave, bf16, from h_hi scratch ----
    union FragU { unsigned int u[4]; short8 s; };
    FragU A0, A1;
    {
        const float* hr = out + obase + (size_t)(wv*16 + m)*64 + q*8;
        const float4 a0 = *(const float4*)(hr);
        const float4 a1 = *(const float4*)(hr + 4);
        const float4 a2 = *(const float4*)(hr + 32);
        const float4 a3 = *(const float4*)(hr + 36);
        A0.u[0]=packbf2(a0.x,a0.y); A0.u[1]=packbf2(a0.z,a0.w);
        A0.u[2]=packbf2(a1.x,a1.y); A0.u[3]=packbf2(a1.z,a1.w);
        A1.u[0]=packbf2(a2.x,a2.y); A1.u[1]=packbf2(a2.z,a2.w);
        A1.u[2]=packbf2(a3.x,a3.y); A1.u[3]=packbf2(a3.z,a3.w);
    }

    // ---- Phase 1: MFMA logits, Z, per-lane top-8 ----
    float tv[4][8]; int ti[4][8]; float zacc[4];
    #pragma unroll
    for (int i=0;i<4;i++) {
        zacc[i] = 0.f;
        #pragma unroll
        for (int s=0;s<8;s++) { tv[i][s] = -INFINITY; ti[i][s] = 0x7fffffff; }
    }
    const int ec = t >> 1, eh2 = t & 1;

    for (int ch=0; ch<16; ++ch) {
        const float* esrc = epool + (size_t)(ch*128 + ec)*DSP + eh2*32;
        float4 f[8];
        #pragma unroll
        for (int g=0;g<8;g++) f[g] = *(const float4*)(esrc + g*4);
        float ss = 0.f;
        #pragma unroll
        for (int g=0;g<8;g++) ss += f[g].x*f[g].x + f[g].y*f[g].y + f[g].z*f[g].z + f[g].w*f[g].w;
        ss += __shfl_xor(ss, 1, 64);
        const float inv = LOG2E_F / fmaxf(sqrtf(ss), 1e-12f);
        __syncthreads();
        #pragma unroll
        for (int g=0;g<8;g++) {
            uint2 u;
            u.x = packbf2(f[g].x*inv, f[g].y*inv);
            u.y = packbf2(f[g].z*inv, f[g].w*inv);
            *(uint2*)&e_bf[ec*68 + eh2*32 + g*4] = u;
        }
        __syncthreads();

        #pragma unroll
        for (int tc=0; tc<8; ++tc) {
            const unsigned int* bp = (const unsigned int*)&e_bf[(tc*16 + m)*68 + q*8];
            FragU B0, B1;
            { uint2 v0 = *(const uint2*)(bp);      B0.u[0]=v0.x; B0.u[1]=v0.y; }
            { uint2 v1 = *(const uint2*)(bp + 2);  B0.u[2]=v1.x; B0.u[3]=v1.y; }
            { uint2 v2 = *(const uint2*)(bp + 16); B1.u[0]=v2.x; B1.u[1]=v2.y; }
            { uint2 v3 = *(const uint2*)(bp + 18); B1.u[2]=v3.x; B1.u[3]=v3.y; }
            f32x4 c = {0.f,0.f,0.f,0.f};
            c = __builtin_amdgcn_mfma_f32_16x16x32_bf16(A0.s, B0.s, c, 0, 0, 0);
            c = __builtin_amdgcn_mfma_f32_16x16x32_bf16(A1.s, B1.s, c, 0, 0, 0);
            const int cidx = ch*128 + tc*16 + m;
            #pragma unroll
            for (int reg=0; reg<4; ++reg) {
                const float w = c[reg];
                zacc[reg] += exp2f(w - C2);
                if (bet_f(w, cidx, tv[reg][7], ti[reg][7])) {
                    tv[reg][7] = w; ti[reg][7] = cidx;
                    #pragma unroll
                    for (int s=7;s>0;--s) {
                        const bool sw = bet_f(tv[reg][s],ti[reg][s],tv[reg][s-1],ti[reg][s-1]);
                        const float a = tv[reg][s]; const int b = ti[reg][s];
                        tv[reg][s]   = sw ? tv[reg][s-1] : tv[reg][s];
                        ti[reg][s]   = sw ? ti[reg][s-1] : ti[reg][s];
                        tv[reg][s-1] = sw ? a : tv[reg][s-1];
                        ti[reg][s-1] = sw ? b : ti[reg][s-1];
                    }
                }
            }
        }
    }

    // ---- Z reduce over the 16 col-lanes of each row ----
    #pragma unroll
    for (int reg=0; reg<4; ++reg) {
        float z = zacc[reg];
        z += __shfl_xor(z, 1, 64);
        z += __shfl_xor(z, 2, 64);
        z += __shfl_xor(z, 4, 64);
        z += __shfl_xor(z, 8, 64);
        if (m == 0) zbuf[wv*16 + q*4 + reg] = z;
    }

    // ---- Merge per-lane top-8 -> per-row top-16 (4 rounds over reg) ----
    for (int i=0;i<4;i++) {
        __syncthreads();
        const int rowslot = wv*4 + q;
        float* cb = cand + (size_t)(rowslot*16 + m)*18;
        #pragma unroll
        for (int s=0;s<8;s++) {
            float2 p; p.x = tv[i][s]; p.y = __int_as_float(ti[i][s]);
            *(float2*)&cb[s*2] = p;
        }
        __syncthreads();
        if (t < 16) {
            float gv[KEEP]; int gi[KEEP];
            #pragma unroll
            for (int s=0;s<KEEP;s++) { gv[s] = -INFINITY; gi[s] = 0x7fffffff; }
            for (int l=0;l<16;l++) {
                const float* cp = cand + (size_t)(t*16 + l)*18;
                #pragma unroll
                for (int s=0;s<8;s++) {
                    const float v  = cp[s*2];
                    const int   ix = __float_as_int(cp[s*2+1]);
                    if (bet_f(v, ix, gv[KEEP-1], gi[KEEP-1])) {
                        gv[KEEP-1] = v; gi[KEEP-1] = ix;
                        #pragma unroll
                        for (int s2=KEEP-1; s2>0; --s2) {
                            const bool sw = bet_f(gv[s2],gi[s2],gv[s2-1],gi[s2-1]);
                            const float a = gv[s2]; const int b = gi[s2];
                            gv[s2]   = sw ? gv[s2-1] : gv[s2];
                            gi[s2]   = sw ? gi[s2-1] : gi[s2];
                            gv[s2-1] = sw ? a : gv[s2-1];
                            gi[s2-1] = sw ? b : gi[s2-1];
                        }
                    }
                }
            }
            const int grow = (t>>2)*16 + (t&3)*4 + i;
            #pragma unroll
            for (int s=0;s<KEEP;s++) ridx16[grow*16 + s] = gi[s];
        }
    }
    __syncthreads();

    // ---- Phase 3: fp64 rescore of the 16 candidates per row ----
    {
        const int row = t >> 2, q4 = t & 3;
        int ixs[4];
        const float* ep[4];
        #pragma unroll
        for (int s=0;s<4;s++) {
            ixs[s] = ridx16[row*16 + q4*4 + s];
            ep[s]  = epool + (size_t)ixs[s]*DSP;
        }
        const float*  hhr = out + obase + (size_t)row*64;
        const ushort* hlr = (const ushort*)(out + obase + 4096) + (size_t)row*64;
        double nn[4] = {0,0,0,0}, dd[4] = {0,0,0,0};
        for (int k4=0; k4<DSP; k4+=4) {
            double h4[4];
            #pragma unroll
            for (int u=0;u<4;u++)
                h4[u] = (double)hhr[k4+u] + (double)bf2f(hlr[k4+u]);
            #pragma unroll
            for (int s=0;s<4;s++) {
                const float4 evv = *(const float4*)(ep[s] + k4);
                const double e0 = (double)evv.x, e1 = (double)evv.y;
                const double e2 = (double)evv.z, e3 = (double)evv.w;
                nn[s] += e0*e0 + e1*e1 + e2*e2 + e3*e3;
                dd[s] += h4[0]*e0 + h4[1]*e1 + h4[2]*e2 + h4[3]*e3;
            }
        }
        #pragma unroll
        for (int s=0;s<4;s++)
            rv[row*17 + q4*4 + s] = dd[s] / fmax(sqrt(nn[s]), 1e-12);
    }
    __syncthreads();

    // ---- Phase 4: fp64 top-8 select, normalize, stash in LDS ----
    if (t < 64) {
        const float Zg = zbuf[t];
        double bv[8]; int oi[8]; float ov[8];
        #pragma unroll
        for (int s=0;s<8;s++) { bv[s] = -INFINITY; oi[s] = 0x7fffffff; }
        for (int s=0;s<KEEP;s++) {
            const double v  = rv[t*17 + s];
            const int    ix = ridx16[t*16 + s];
            if (bet_d(v, ix, bv[7], oi[7])) {
                bv[7] = v; oi[7] = ix;
                #pragma unroll
                for (int s2=7; s2>0; --s2) {
                    const bool sw = bet_d(bv[s2],oi[s2],bv[s2-1],oi[s2-1]);
                    const double a = bv[s2]; const int b = oi[s2];
                    bv[s2]   = sw ? bv[s2-1] : bv[s2];
                    oi[s2]   = sw ? oi[s2-1] : oi[s2];
                    bv[s2-1] = sw ? a : bv[s2-1];
                    oi[s2-1] = sw ? b : oi[s2-1];
                }
            }
        }
        float denom = 1e-8f * Zg;
        #pragma unroll
        for (int s=0;s<8;s++) {
            ov[s] = exp2f((float)(bv[s]*LOG2E_D) - C2);
            denom += ov[s];
        }
        const float rd = 1.0f / denom;
        #pragma unroll
        for (int s=0;s<8;s++) {
            float2 p; p.x = ov[s]*rd; p.y = __int_as_float(oi[s]);
            *(float2*)&final8[t*16 + s*2] = p;
        }
    }
    __syncthreads();   // drains rescore loads + final8 stores before overwrite

    // ---- Phase 5: merged zero+scatter burst write (one visit per line) ----
    for (int rr=0; rr<16; ++rr) {
        const int row = rr*4 + wv;          // one row per wave
        float pv[8]; int pi[8];
        #pragma unroll
        for (int s=0;s<8;s++) {             // broadcast LDS reads
            pv[s] = final8[row*16 + s*2];
            pi[s] = __float_as_int(final8[row*16 + s*2 + 1]);
        }
        float* orow = out + obase + (size_t)row*NPOOL;
        #pragma unroll
        for (int j=0;j<8;j++) {
            const int f4i = j*64 + lane;
            float v0=0.f, v1=0.f, v2=0.f, v3=0.f;
            #pragma unroll
            for (int s=0;s<8;s++) {
                const int d = pi[s] - f4i*4;
                v0 = (d==0) ? pv[s] : v0;
                v1 = (d==1) ? pv[s] : v1;
                v2 = (d==2) ? pv[s] : v2;
                v3 = (d==3) ? pv[s] : v3;
            }
            *(float4*)&orow[f4i*4] = make_float4(v0,v1,v2,v3);
        }
    }
}

extern "C" void kernel_launch(void* const* d_in, const int* in_sizes, int n_in,
                              void* d_out, int out_size, void* d_ws, size_t ws_size,
                              hipStream_t stream) {
    (void)in_sizes; (void)n_in; (void)d_ws; (void)ws_size; (void)out_size;
    const float* x   = (const float*)d_in[0];
    const float* Wm  = (const float*)d_in[1];
    const float* bb  = (const float*)d_in[2];
    const float* emb = (const float*)d_in[3];
    float* out = (float*)d_out;
    dim3 grid(NROWS / TILE_M, HEADS);
    proj_k <<<grid, dim3(256), 0, stream>>>(x, Wm, bb, out);
    route_k<<<grid, dim3(256), 0, stream>>>(emb, out);
}

// Round 4
// 2504.250 us; speedup vs baseline: 6.0697x; 6.0697x over previous
//
#include <hip/hip_runtime.h>
#include <hip/hip_bf16.h>
#include <math.h>

#define HEADS   6
#define DMODEL  1024
#define NPROJ   384
#define DSP     64
#define NPOOL   2048
#define NROWS   8192
#define TILE_M  64
#define KT      64
#define KEEP    16

#define LOG2E_F 1.44269504088896340f
#define LOG2E_D 1.4426950408889634
#define C2      14.4269504088896340f   /* 10*log2(e); |logit| provably < 10 */

typedef __attribute__((ext_vector_type(8))) short short8;
typedef __attribute__((ext_vector_type(4))) float f32x4;

__device__ __forceinline__ bool bet_f(float v, int vi, float w, int wi) {
    return (v > w) || (v == w && vi < wi);
}
__device__ __forceinline__ bool bet_d(double v, int vi, double w, int wi) {
    return (v > w) || (v == w && vi < wi);
}
__device__ __forceinline__ unsigned short f2bf(float f) {   // RNE, no NaN inputs
    unsigned int u = __float_as_uint(f);
    return (unsigned short)((u + 0x7fffu + ((u >> 16) & 1u)) >> 16);
}
__device__ __forceinline__ float bf2f(unsigned short s) {
    return __uint_as_float(((unsigned int)s) << 16);
}
__device__ __forceinline__ unsigned int packbf2(float a, float b) {
    return (unsigned int)f2bf(a) | ((unsigned int)f2bf(b) << 16);
}

// ======================= Kernel 1: fp64 projection =======================
// h (64 rows x 64 cols per block) written into the block's own output region:
//   h_hi f32 [64][64] at out+obase, h_lo bf16 [64][64] at out+obase+4096 floats.
__global__ __launch_bounds__(256, 3)
void proj_k(const float* __restrict__ x, const float* __restrict__ Wm,
            const float* __restrict__ bb, float* __restrict__ out)
{
    __shared__ __align__(16) float stage[64*68];  // x tile, [k][row]

    const int t    = threadIdx.x;
    const int cg   = t & 15;
    const int rg   = t >> 4;
    const int head = blockIdx.y;
    const int row0 = blockIdx.x * TILE_M;
    const size_t obase = ((size_t)head*NROWS + row0) * (size_t)NPOOL;

    double acc0[4][4];
    #pragma unroll
    for (int i=0;i<4;i++) {
        #pragma unroll
        for (int j=0;j<4;j++) acc0[i][j] = 0.0;
    }
    const int xr = t >> 2;
    const int xq = t & 3;
    const float* wcol = Wm + head*64 + cg*4;

    for (int kk = 0; kk < DMODEL; kk += KT) {
        const float* xsrc = x + (size_t)(row0+xr)*DMODEL + kk + xq*16;
        float4 xv[4];
        #pragma unroll
        for (int q=0;q<4;q++) xv[q] = *(const float4*)(xsrc + q*4);
        __syncthreads();
        #pragma unroll
        for (int q=0;q<4;q++) {
            const int k = xq*16 + q*4;
            stage[(k+0)*68 + xr] = xv[q].x;
            stage[(k+1)*68 + xr] = xv[q].y;
            stage[(k+2)*68 + xr] = xv[q].z;
            stage[(k+3)*68 + xr] = xv[q].w;
        }
        __syncthreads();
        const float* wk = wcol + (size_t)kk*NPROJ;
        #pragma unroll 4
        for (int k=0;k<KT;k++) {
            const float4 xf = *(const float4*)&stage[k*68 + rg*4];
            const float4 wf = *(const float4*)(wk + (size_t)k*NPROJ);
            const double xd[4] = {(double)xf.x,(double)xf.y,(double)xf.z,(double)xf.w};
            const double wd[4] = {(double)wf.x,(double)wf.y,(double)wf.z,(double)wf.w};
            #pragma unroll
            for (int i=0;i<4;i++) {
                #pragma unroll
                for (int j=0;j<4;j++)
                    acc0[i][j] = fma(xd[i], wd[j], acc0[i][j]);
            }
        }
    }

    float*  hhi = out + obase;                       // [64][64] f32
    ushort* hlo = (ushort*)(out + obase + 4096);     // [64][64] bf16
    #pragma unroll
    for (int i=0;i<4;i++) {
        float4  hv; ushort4 lv;
        double vv[4];
        #pragma unroll
        for (int j=0;j<4;j++) vv[j] = acc0[i][j] + (double)bb[head*64 + cg*4 + j];
        hv.x=(float)vv[0]; hv.y=(float)vv[1]; hv.z=(float)vv[2]; hv.w=(float)vv[3];
        lv.x=f2bf((float)(vv[0]-(double)hv.x)); lv.y=f2bf((float)(vv[1]-(double)hv.y));
        lv.z=f2bf((float)(vv[2]-(double)hv.z)); lv.w=f2bf((float)(vv[3]-(double)hv.w));
        *(float4*) &hhi[(size_t)(rg*4+i)*64 + cg*4] = hv;
        *(ushort4*)&hlo[(size_t)(rg*4+i)*64 + cg*4] = lv;
    }
}

// ======================= Kernel 2: router =======================
__global__ __launch_bounds__(256, 3)
void route_k(const float* __restrict__ emb, float* __restrict__ out)
{
    __shared__ __align__(16) double smem_d[2304];   // 18432 B multi-use
    __shared__ int   ridx16[64*16];                 // 4096 B
    __shared__ float zbuf[64];
    float*  cand   = (float*)smem_d;                // [256][18] (merge)
    double* rv     = smem_d;                        // [64][17]  (rescore)
    float*  final8 = ((float*)smem_d) + 2304;       // [64][16]  (bytes 9216..13312)

    const int t    = threadIdx.x;
    const int lane = t & 63, wv = t >> 6;
    const int m    = lane & 15, q = lane >> 4;
    const int head = blockIdx.y;
    const int row0 = blockIdx.x * TILE_M;
    const size_t obase = ((size_t)head*NROWS + row0) * (size_t)NPOOL;

    int psel = 0;                 // pools: [fqk,fqk,fv,rqk,rqk,rv]
    if (head >= 2) psel = 1;
    if (head >= 3) psel = 2;
    if (head >= 5) psel = 3;
    const float* epool = emb + (size_t)psel * NPOOL * DSP;

    // ---- A fragments: h rows of this wave, bf16, from h_hi scratch ----
    union FragU { unsigned int u[4]; short8 s; };
    FragU A0, A1;
    {
        const float* hr = out + obase + (size_t)(wv*16 + m)*64 + q*8;
        const float4 a0 = *(const float4*)(hr);
        const float4 a1 = *(const float4*)(hr + 4);
        const float4 a2 = *(const float4*)(hr + 32);
        const float4 a3 = *(const float4*)(hr + 36);
        A0.u[0]=packbf2(a0.x,a0.y); A0.u[1]=packbf2(a0.z,a0.w);
        A0.u[2]=packbf2(a1.x,a1.y); A0.u[3]=packbf2(a1.z,a1.w);
        A1.u[0]=packbf2(a2.x,a2.y); A1.u[1]=packbf2(a2.z,a2.w);
        A1.u[2]=packbf2(a3.x,a3.y); A1.u[3]=packbf2(a3.z,a3.w);
    }

    // ---- Phase 1: MFMA logits, Z, per-lane top-8; B-frags straight from global ----
    float tv[4][8]; int ti[4][8]; float zacc[4];
    #pragma unroll
    for (int i=0;i<4;i++) {
        zacc[i] = 0.f;
        #pragma unroll
        for (int s=0;s<8;s++) { tv[i][s] = -INFINITY; ti[i][s] = 0x7fffffff; }
    }

    for (int ch=0; ch<16; ++ch) {
        #pragma unroll 2
        for (int tc=0; tc<8; ++tc) {
            const int cidx = ch*128 + tc*16 + m;            // e row this lane needs
            const float* er = epool + (size_t)cidx*DSP + q*8;
            const float4 e0 = *(const float4*)(er);
            const float4 e1 = *(const float4*)(er + 4);
            const float4 e2 = *(const float4*)(er + 32);
            const float4 e3 = *(const float4*)(er + 36);
            float ss = e0.x*e0.x + e0.y*e0.y + e0.z*e0.z + e0.w*e0.w
                     + e1.x*e1.x + e1.y*e1.y + e1.z*e1.z + e1.w*e1.w
                     + e2.x*e2.x + e2.y*e2.y + e2.z*e2.z + e2.w*e2.w
                     + e3.x*e3.x + e3.y*e3.y + e3.z*e3.z + e3.w*e3.w;
            ss += __shfl_xor(ss, 16, 64);
            ss += __shfl_xor(ss, 32, 64);
            const float inv = LOG2E_F / fmaxf(sqrtf(ss), 1e-12f);
            FragU B0, B1;
            B0.u[0]=packbf2(e0.x*inv, e0.y*inv); B0.u[1]=packbf2(e0.z*inv, e0.w*inv);
            B0.u[2]=packbf2(e1.x*inv, e1.y*inv); B0.u[3]=packbf2(e1.z*inv, e1.w*inv);
            B1.u[0]=packbf2(e2.x*inv, e2.y*inv); B1.u[1]=packbf2(e2.z*inv, e2.w*inv);
            B1.u[2]=packbf2(e3.x*inv, e3.y*inv); B1.u[3]=packbf2(e3.z*inv, e3.w*inv);

            f32x4 c = {0.f,0.f,0.f,0.f};
            c = __builtin_amdgcn_mfma_f32_16x16x32_bf16(A0.s, B0.s, c, 0, 0, 0);
            c = __builtin_amdgcn_mfma_f32_16x16x32_bf16(A1.s, B1.s, c, 0, 0, 0);
            #pragma unroll
            for (int reg=0; reg<4; ++reg) {
                const float w = c[reg];
                zacc[reg] += exp2f(w - C2);
                if (bet_f(w, cidx, tv[reg][7], ti[reg][7])) {
                    tv[reg][7] = w; ti[reg][7] = cidx;
                    #pragma unroll
                    for (int s=7;s>0;--s) {
                        const bool sw = bet_f(tv[reg][s],ti[reg][s],tv[reg][s-1],ti[reg][s-1]);
                        const float a = tv[reg][s]; const int b = ti[reg][s];
                        tv[reg][s]   = sw ? tv[reg][s-1] : tv[reg][s];
                        ti[reg][s]   = sw ? ti[reg][s-1] : ti[reg][s];
                        tv[reg][s-1] = sw ? a : tv[reg][s-1];
                        ti[reg][s-1] = sw ? b : ti[reg][s-1];
                    }
                }
            }
        }
    }

    // ---- Z reduce over the 16 col-lanes of each row ----
    #pragma unroll
    for (int reg=0; reg<4; ++reg) {
        float z = zacc[reg];
        z += __shfl_xor(z, 1, 64);
        z += __shfl_xor(z, 2, 64);
        z += __shfl_xor(z, 4, 64);
        z += __shfl_xor(z, 8, 64);
        if (m == 0) zbuf[wv*16 + q*4 + reg] = z;
    }

    // ---- Merge per-lane top-8 -> per-row top-16 (4 rounds over reg) ----
    for (int i=0;i<4;i++) {
        __syncthreads();
        const int rowslot = wv*4 + q;
        float* cb = cand + (size_t)(rowslot*16 + m)*18;
        #pragma unroll
        for (int s=0;s<8;s++) {
            float2 p; p.x = tv[i][s]; p.y = __int_as_float(ti[i][s]);
            *(float2*)&cb[s*2] = p;
        }
        __syncthreads();
        if (t < 16) {
            float gv[KEEP]; int gi[KEEP];
            #pragma unroll
            for (int s=0;s<KEEP;s++) { gv[s] = -INFINITY; gi[s] = 0x7fffffff; }
            for (int l=0;l<16;l++) {
                const float* cp = cand + (size_t)(t*16 + l)*18;
                #pragma unroll
                for (int s=0;s<8;s++) {
                    const float v  = cp[s*2];
                    const int   ix = __float_as_int(cp[s*2+1]);
                    if (bet_f(v, ix, gv[KEEP-1], gi[KEEP-1])) {
                        gv[KEEP-1] = v; gi[KEEP-1] = ix;
                        #pragma unroll
                        for (int s2=KEEP-1; s2>0; --s2) {
                            const bool sw = bet_f(gv[s2],gi[s2],gv[s2-1],gi[s2-1]);
                            const float a = gv[s2]; const int b = gi[s2];
                            gv[s2]   = sw ? gv[s2-1] : gv[s2];
                            gi[s2]   = sw ? gi[s2-1] : gi[s2];
                            gv[s2-1] = sw ? a : gv[s2-1];
                            gi[s2-1] = sw ? b : gi[s2-1];
                        }
                    }
                }
            }
            const int grow = (t>>2)*16 + (t&3)*4 + i;
            #pragma unroll
            for (int s=0;s<KEEP;s++) ridx16[grow*16 + s] = gi[s];
        }
    }
    __syncthreads();

    // ---- Phase 3: fp64 rescore of the 16 candidates per row ----
    {
        const int row = t >> 2, q4 = t & 3;
        int ixs[4];
        const float* ep[4];
        #pragma unroll
        for (int s=0;s<4;s++) {
            ixs[s] = ridx16[row*16 + q4*4 + s];
            ep[s]  = epool + (size_t)ixs[s]*DSP;
        }
        const float*  hhr = out + obase + (size_t)row*64;
        const ushort* hlr = (const ushort*)(out + obase + 4096) + (size_t)row*64;
        double nn[4] = {0,0,0,0}, dd[4] = {0,0,0,0};
        for (int k4=0; k4<DSP; k4+=4) {
            double h4[4];
            #pragma unroll
            for (int u=0;u<4;u++)
                h4[u] = (double)hhr[k4+u] + (double)bf2f(hlr[k4+u]);
            #pragma unroll
            for (int s=0;s<4;s++) {
                const float4 evv = *(const float4*)(ep[s] + k4);
                const double e0 = (double)evv.x, e1 = (double)evv.y;
                const double e2 = (double)evv.z, e3 = (double)evv.w;
                nn[s] += e0*e0 + e1*e1 + e2*e2 + e3*e3;
                dd[s] += h4[0]*e0 + h4[1]*e1 + h4[2]*e2 + h4[3]*e3;
            }
        }
        #pragma unroll
        for (int s=0;s<4;s++)
            rv[row*17 + q4*4 + s] = dd[s] / fmax(sqrt(nn[s]), 1e-12);
    }
    __syncthreads();

    // ---- Phase 4: fp64 top-8 select, normalize, stash in LDS ----
    if (t < 64) {
        const float Zg = zbuf[t];
        double bv[8]; int oi[8]; float ov[8];
        #pragma unroll
        for (int s=0;s<8;s++) { bv[s] = -INFINITY; oi[s] = 0x7fffffff; }
        for (int s=0;s<KEEP;s++) {
            const double v  = rv[t*17 + s];
            const int    ix = ridx16[t*16 + s];
            if (bet_d(v, ix, bv[7], oi[7])) {
                bv[7] = v; oi[7] = ix;
                #pragma unroll
                for (int s2=7; s2>0; --s2) {
                    const bool sw = bet_d(bv[s2],oi[s2],bv[s2-1],oi[s2-1]);
                    const double a = bv[s2]; const int b = oi[s2];
                    bv[s2]   = sw ? bv[s2-1] : bv[s2];
                    oi[s2]   = sw ? oi[s2-1] : oi[s2];
                    bv[s2-1] = sw ? a : bv[s2-1];
                    oi[s2-1] = sw ? b : oi[s2-1];
                }
            }
        }
        float denom = 1e-8f * Zg;
        #pragma unroll
        for (int s=0;s<8;s++) {
            ov[s] = exp2f((float)(bv[s]*LOG2E_D) - C2);
            denom += ov[s];
        }
        const float rd = 1.0f / denom;
        #pragma unroll
        for (int s=0;s<8;s++) {
            float2 p; p.x = ov[s]*rd; p.y = __int_as_float(oi[s]);
            *(float2*)&final8[t*16 + s*2] = p;
        }
    }
    __syncthreads();   // drains rescore loads + final8 stores before overwrite

    // ---- Phase 5: merged zero+scatter burst write (one visit per line) ----
    for (int rr=0; rr<16; ++rr) {
        const int row = rr*4 + wv;          // one row per wave
        float pv[8]; int pi[8];
        #pragma unroll
        for (int s=0;s<8;s++) {             // broadcast LDS reads
            pv[s] = final8[row*16 + s*2];
            pi[s] = __float_as_int(final8[row*16 + s*2 + 1]);
        }
        float* orow = out + obase + (size_t)row*NPOOL;
        #pragma unroll
        for (int j=0;j<8;j++) {
            const int f4i = j*64 + lane;
            float v0=0.f, v1=0.f, v2=0.f, v3=0.f;
            #pragma unroll
            for (int s=0;s<8;s++) {
                const int d = pi[s] - f4i*4;
                v0 = (d==0) ? pv[s] : v0;
                v1 = (d==1) ? pv[s] : v1;
                v2 = (d==2) ? pv[s] : v2;
                v3 = (d==3) ? pv[s] : v3;
            }
            *(float4*)&orow[f4i*4] = make_float4(v0,v1,v2,v3);
        }
    }
}

extern "C" void kernel_launch(void* const* d_in, const int* in_sizes, int n_in,
                              void* d_out, int out_size, void* d_ws, size_t ws_size,
                              hipStream_t stream) {
    (void)in_sizes; (void)n_in; (void)d_ws; (void)ws_size; (void)out_size;
    const float* x   = (const float*)d_in[0];
    const float* Wm  = (const float*)d_in[1];
    const float* bb  = (const float*)d_in[2];
    const float* emb = (const float*)d_in[3];
    float* out = (float*)d_out;
    dim3 grid(NROWS / TILE_M, HEADS);
    proj_k <<<grid, dim3(256), 0, stream>>>(x, Wm, bb, out);
    route_k<<<grid, dim3(256), 0, stream>>>(emb, out);
}

// Round 5
// 2390.885 us; speedup vs baseline: 6.3575x; 1.0474x over previous
//
#include <hip/hip_runtime.h>
#include <hip/hip_bf16.h>
#include <math.h>

#define HEADS   6
#define DMODEL  1024
#define NPROJ   384
#define DSP     64
#define NPOOL   2048
#define NROWS   8192
#define TILE_M  64
#define KT      64
#define KEEP    16

#define LOG2E_F 1.44269504088896340f
#define LOG2E_D 1.4426950408889634
#define C2      14.4269504088896340f   /* 10*log2(e); |logit| provably < 10 */

typedef __attribute__((ext_vector_type(8))) short short8;
typedef __attribute__((ext_vector_type(4))) float f32x4;

__device__ __forceinline__ bool bet_f(float v, int vi, float w, int wi) {
    return (v > w) || (v == w && vi < wi);
}
__device__ __forceinline__ bool bet_d(double v, int vi, double w, int wi) {
    return (v > w) || (v == w && vi < wi);
}
__device__ __forceinline__ unsigned short f2bf(float f) {   // RNE, no NaN inputs
    unsigned int u = __float_as_uint(f);
    return (unsigned short)((u + 0x7fffu + ((u >> 16) & 1u)) >> 16);
}
__device__ __forceinline__ float bf2f(unsigned short s) {
    return __uint_as_float(((unsigned int)s) << 16);
}
__device__ __forceinline__ unsigned int packbf2(float a, float b) {
    return (unsigned int)f2bf(a) | ((unsigned int)f2bf(b) << 16);
}

// ======================= Kernel 1: fp64 projection =======================
// h (64 rows x 64 cols per block) written into the block's own output region:
//   h_hi f32 [64][64] at out+obase, h_lo bf16 [64][64] at out+obase+4096 floats.
// W staged in LDS; global loads for tile k+1 issued before compute of tile k.
__global__ __launch_bounds__(256, 3)
void proj_k(const float* __restrict__ x, const float* __restrict__ Wm,
            const float* __restrict__ bb, float* __restrict__ out)
{
    __shared__ __align__(16) float x_t[64*68];   // [k][row]
    __shared__ __align__(16) float w_t[64*68];   // [k][col]

    const int t    = threadIdx.x;
    const int cg   = t & 15;
    const int rg   = t >> 4;
    const int head = blockIdx.y;
    const int row0 = blockIdx.x * TILE_M;
    const size_t obase = ((size_t)head*NROWS + row0) * (size_t)NPOOL;

    double acc0[4][4];
    #pragma unroll
    for (int i=0;i<4;i++) {
        #pragma unroll
        for (int j=0;j<4;j++) acc0[i][j] = 0.0;
    }
    const int xr = t >> 2;        // 0..63 row
    const int xq = t & 3;         // k quarter (16 k's)
    const int wr = t >> 4;        // 0..15 base k-row for W
    const float* wbase = Wm + head*64 + cg*4;

    float4 xv[4], wv[4];
    // preload tile 0
    {
        const float* xsrc = x + (size_t)(row0+xr)*DMODEL + xq*16;
        #pragma unroll
        for (int q=0;q<4;q++) xv[q] = *(const float4*)(xsrc + q*4);
        #pragma unroll
        for (int j=0;j<4;j++)
            wv[j] = *(const float4*)(wbase + (size_t)(wr + 16*j)*NPROJ);
    }

    for (int kk = 0; kk < DMODEL; kk += KT) {
        __syncthreads();   // prev tile's LDS reads done
        #pragma unroll
        for (int q=0;q<4;q++) {
            const int k = xq*16 + q*4;
            x_t[(k+0)*68 + xr] = xv[q].x;
            x_t[(k+1)*68 + xr] = xv[q].y;
            x_t[(k+2)*68 + xr] = xv[q].z;
            x_t[(k+3)*68 + xr] = xv[q].w;
        }
        #pragma unroll
        for (int j=0;j<4;j++)
            *(float4*)&w_t[(wr + 16*j)*68 + cg*4] = wv[j];
        __syncthreads();
        // prefetch next tile while computing this one
        if (kk + KT < DMODEL) {
            const float* xsrc = x + (size_t)(row0+xr)*DMODEL + (kk+KT) + xq*16;
            #pragma unroll
            for (int q=0;q<4;q++) xv[q] = *(const float4*)(xsrc + q*4);
            #pragma unroll
            for (int j=0;j<4;j++)
                wv[j] = *(const float4*)(wbase + (size_t)(kk+KT + wr + 16*j)*NPROJ);
        }
        #pragma unroll 4
        for (int k=0;k<KT;k++) {
            const float4 xf = *(const float4*)&x_t[k*68 + rg*4];
            const float4 wf = *(const float4*)&w_t[k*68 + cg*4];
            const double xd[4] = {(double)xf.x,(double)xf.y,(double)xf.z,(double)xf.w};
            const double wd[4] = {(double)wf.x,(double)wf.y,(double)wf.z,(double)wf.w};
            #pragma unroll
            for (int i=0;i<4;i++) {
                #pragma unroll
                for (int j=0;j<4;j++)
                    acc0[i][j] = fma(xd[i], wd[j], acc0[i][j]);
            }
        }
    }

    float*  hhi = out + obase;                       // [64][64] f32
    ushort* hlo = (ushort*)(out + obase + 4096);     // [64][64] bf16
    #pragma unroll
    for (int i=0;i<4;i++) {
        float4  hv; ushort4 lv;
        double vv[4];
        #pragma unroll
        for (int j=0;j<4;j++) vv[j] = acc0[i][j] + (double)bb[head*64 + cg*4 + j];
        hv.x=(float)vv[0]; hv.y=(float)vv[1]; hv.z=(float)vv[2]; hv.w=(float)vv[3];
        lv.x=f2bf((float)(vv[0]-(double)hv.x)); lv.y=f2bf((float)(vv[1]-(double)hv.y));
        lv.z=f2bf((float)(vv[2]-(double)hv.z)); lv.w=f2bf((float)(vv[3]-(double)hv.w));
        *(float4*) &hhi[(size_t)(rg*4+i)*64 + cg*4] = hv;
        *(ushort4*)&hlo[(size_t)(rg*4+i)*64 + cg*4] = lv;
    }
}

// ======================= Kernel 2: router =======================
__global__ __launch_bounds__(256, 3)
void route_k(const float* __restrict__ emb, float* __restrict__ out)
{
    __shared__ __align__(16) double smem_d[2304];   // 18432 B multi-use
    __shared__ int   ridx16[64*16];                 // 4096 B
    __shared__ float zbuf[64];
    float*  cand   = (float*)smem_d;                // [256][18] (merge)
    double* rv     = smem_d;                        // [64][17]  (rescore)
    float*  final8 = ((float*)smem_d) + 2304;       // [64][16]  (bytes 9216..13312)

    const int t    = threadIdx.x;
    const int lane = t & 63, wv = t >> 6;
    const int m    = lane & 15, q = lane >> 4;
    const int head = blockIdx.y;
    const int row0 = blockIdx.x * TILE_M;
    const size_t obase = ((size_t)head*NROWS + row0) * (size_t)NPOOL;

    int psel = 0;                 // pools: [fqk,fqk,fv,rqk,rqk,rv]
    if (head >= 2) psel = 1;
    if (head >= 3) psel = 2;
    if (head >= 5) psel = 3;
    const float* epool = emb + (size_t)psel * NPOOL * DSP;

    // ---- A fragments: h rows of this wave, bf16, from h_hi scratch ----
    union FragU { unsigned int u[4]; short8 s; };
    FragU A0, A1;
    {
        const float* hr = out + obase + (size_t)(wv*16 + m)*64 + q*8;
        const float4 a0 = *(const float4*)(hr);
        const float4 a1 = *(const float4*)(hr + 4);
        const float4 a2 = *(const float4*)(hr + 32);
        const float4 a3 = *(const float4*)(hr + 36);
        A0.u[0]=packbf2(a0.x,a0.y); A0.u[1]=packbf2(a0.z,a0.w);
        A0.u[2]=packbf2(a1.x,a1.y); A0.u[3]=packbf2(a1.z,a1.w);
        A1.u[0]=packbf2(a2.x,a2.y); A1.u[1]=packbf2(a2.z,a2.w);
        A1.u[2]=packbf2(a3.x,a3.y); A1.u[3]=packbf2(a3.z,a3.w);
    }

    // ---- Phase 1: MFMA logits, Z, per-lane top-8; B-frags straight from global ----
    // NOTE: every access to tv/ti below is in a #pragma unroll'd loop (constant
    // indices) — one runtime index would demote these arrays to scratch (R3/R4 bug).
    float tv[4][8]; int ti[4][8]; float zacc[4];
    #pragma unroll
    for (int i=0;i<4;i++) {
        zacc[i] = 0.f;
        #pragma unroll
        for (int s=0;s<8;s++) { tv[i][s] = -INFINITY; ti[i][s] = 0x7fffffff; }
    }

    #pragma unroll 1
    for (int it=0; it<128; ++it) {
        const int cidx = it*16 + m;                 // e row this lane needs
        const float* er = epool + (size_t)cidx*DSP + q*8;
        const float4 e0 = *(const float4*)(er);
        const float4 e1 = *(const float4*)(er + 4);
        const float4 e2 = *(const float4*)(er + 32);
        const float4 e3 = *(const float4*)(er + 36);
        float ss = e0.x*e0.x + e0.y*e0.y + e0.z*e0.z + e0.w*e0.w
                 + e1.x*e1.x + e1.y*e1.y + e1.z*e1.z + e1.w*e1.w
                 + e2.x*e2.x + e2.y*e2.y + e2.z*e2.z + e2.w*e2.w
                 + e3.x*e3.x + e3.y*e3.y + e3.z*e3.z + e3.w*e3.w;
        ss += __shfl_xor(ss, 16, 64);
        ss += __shfl_xor(ss, 32, 64);
        const float inv = LOG2E_F / fmaxf(sqrtf(ss), 1e-12f);
        FragU B0, B1;
        B0.u[0]=packbf2(e0.x*inv, e0.y*inv); B0.u[1]=packbf2(e0.z*inv, e0.w*inv);
        B0.u[2]=packbf2(e1.x*inv, e1.y*inv); B0.u[3]=packbf2(e1.z*inv, e1.w*inv);
        B1.u[0]=packbf2(e2.x*inv, e2.y*inv); B1.u[1]=packbf2(e2.z*inv, e2.w*inv);
        B1.u[2]=packbf2(e3.x*inv, e3.y*inv); B1.u[3]=packbf2(e3.z*inv, e3.w*inv);

        f32x4 c = {0.f,0.f,0.f,0.f};
        c = __builtin_amdgcn_mfma_f32_16x16x32_bf16(A0.s, B0.s, c, 0, 0, 0);
        c = __builtin_amdgcn_mfma_f32_16x16x32_bf16(A1.s, B1.s, c, 0, 0, 0);
        #pragma unroll
        for (int reg=0; reg<4; ++reg) {
            const float w = c[reg];
            zacc[reg] += exp2f(w - C2);
            if (bet_f(w, cidx, tv[reg][7], ti[reg][7])) {
                tv[reg][7] = w; ti[reg][7] = cidx;
                #pragma unroll
                for (int s=7;s>0;--s) {
                    const bool sw = bet_f(tv[reg][s],ti[reg][s],tv[reg][s-1],ti[reg][s-1]);
                    const float a = tv[reg][s]; const int b = ti[reg][s];
                    tv[reg][s]   = sw ? tv[reg][s-1] : tv[reg][s];
                    ti[reg][s]   = sw ? ti[reg][s-1] : ti[reg][s];
                    tv[reg][s-1] = sw ? a : tv[reg][s-1];
                    ti[reg][s-1] = sw ? b : ti[reg][s-1];
                }
            }
        }
    }

    // ---- Z reduce over the 16 col-lanes of each row ----
    #pragma unroll
    for (int reg=0; reg<4; ++reg) {
        float z = zacc[reg];
        z += __shfl_xor(z, 1, 64);
        z += __shfl_xor(z, 2, 64);
        z += __shfl_xor(z, 4, 64);
        z += __shfl_xor(z, 8, 64);
        if (m == 0) zbuf[wv*16 + q*4 + reg] = z;
    }

    // ---- Merge per-lane top-8 -> per-row top-16 (4 rounds over reg i) ----
    #pragma unroll
    for (int i=0;i<4;i++) {
        __syncthreads();
        const int rowslot = wv*4 + q;
        float* cb = cand + (size_t)(rowslot*16 + m)*18;
        #pragma unroll
        for (int s=0;s<8;s++) {
            float2 p; p.x = tv[i][s]; p.y = __int_as_float(ti[i][s]);
            *(float2*)&cb[s*2] = p;
        }
        __syncthreads();
        if (t < 16) {
            float gv[KEEP]; int gi[KEEP];
            #pragma unroll
            for (int s=0;s<KEEP;s++) { gv[s] = -INFINITY; gi[s] = 0x7fffffff; }
            #pragma unroll 1
            for (int l=0;l<16;l++) {
                const float* cp = cand + (size_t)(t*16 + l)*18;
                #pragma unroll
                for (int s=0;s<8;s++) {
                    const float v  = cp[s*2];
                    const int   ix = __float_as_int(cp[s*2+1]);
                    if (bet_f(v, ix, gv[KEEP-1], gi[KEEP-1])) {
                        gv[KEEP-1] = v; gi[KEEP-1] = ix;
                        #pragma unroll
                        for (int s2=KEEP-1; s2>0; --s2) {
                            const bool sw = bet_f(gv[s2],gi[s2],gv[s2-1],gi[s2-1]);
                            const float a = gv[s2]; const int b = gi[s2];
                            gv[s2]   = sw ? gv[s2-1] : gv[s2];
                            gi[s2]   = sw ? gi[s2-1] : gi[s2];
                            gv[s2-1] = sw ? a : gv[s2-1];
                            gi[s2-1] = sw ? b : gi[s2-1];
                        }
                    }
                }
            }
            const int grow = (t>>2)*16 + (t&3)*4 + i;
            #pragma unroll
            for (int s=0;s<KEEP;s++) ridx16[grow*16 + s] = gi[s];
        }
    }
    __syncthreads();

    // ---- Phase 3: fp64 rescore of the 16 candidates per row ----
    {
        const int row = t >> 2, q4 = t & 3;
        int ixs[4];
        const float* ep[4];
        #pragma unroll
        for (int s=0;s<4;s++) {
            ixs[s] = ridx16[row*16 + q4*4 + s];
            ep[s]  = epool + (size_t)ixs[s]*DSP;
        }
        const float*  hhr = out + obase + (size_t)row*64;
        const ushort* hlr = (const ushort*)(out + obase + 4096) + (size_t)row*64;
        double nn[4] = {0,0,0,0}, dd[4] = {0,0,0,0};
        #pragma unroll 1
        for (int k4=0; k4<DSP; k4+=4) {
            double h4[4];
            #pragma unroll
            for (int u=0;u<4;u++)
                h4[u] = (double)hhr[k4+u] + (double)bf2f(hlr[k4+u]);
            #pragma unroll
            for (int s=0;s<4;s++) {
                const float4 evv = *(const float4*)(ep[s] + k4);
                const double e0 = (double)evv.x, e1 = (double)evv.y;
                const double e2 = (double)evv.z, e3 = (double)evv.w;
                nn[s] += e0*e0 + e1*e1 + e2*e2 + e3*e3;
                dd[s] += h4[0]*e0 + h4[1]*e1 + h4[2]*e2 + h4[3]*e3;
            }
        }
        #pragma unroll
        for (int s=0;s<4;s++)
            rv[row*17 + q4*4 + s] = dd[s] / fmax(sqrt(nn[s]), 1e-12);
    }
    __syncthreads();

    // ---- Phase 4: fp64 top-8 select, normalize, stash in LDS ----
    if (t < 64) {
        const float Zg = zbuf[t];
        double bv[8]; int oi[8]; float ov[8];
        #pragma unroll
        for (int s=0;s<8;s++) { bv[s] = -INFINITY; oi[s] = 0x7fffffff; }
        #pragma unroll 1
        for (int s=0;s<KEEP;s++) {
            const double v  = rv[t*17 + s];
            const int    ix = ridx16[t*16 + s];
            if (bet_d(v, ix, bv[7], oi[7])) {
                bv[7] = v; oi[7] = ix;
                #pragma unroll
                for (int s2=7; s2>0; --s2) {
                    const bool sw = bet_d(bv[s2],oi[s2],bv[s2-1],oi[s2-1]);
                    const double a = bv[s2]; const int b = oi[s2];
                    bv[s2]   = sw ? bv[s2-1] : bv[s2];
                    oi[s2]   = sw ? oi[s2-1] : oi[s2];
                    bv[s2-1] = sw ? a : bv[s2-1];
                    oi[s2-1] = sw ? b : oi[s2-1];
                }
            }
        }
        float denom = 1e-8f * Zg;
        #pragma unroll
        for (int s=0;s<8;s++) {
            ov[s] = exp2f((float)(bv[s]*LOG2E_D) - C2);
            denom += ov[s];
        }
        const float rd = 1.0f / denom;
        #pragma unroll
        for (int s=0;s<8;s++) {
            float2 p; p.x = ov[s]*rd; p.y = __int_as_float(oi[s]);
            *(float2*)&final8[t*16 + s*2] = p;
        }
    }
    __syncthreads();   // drains rescore loads + final8 stores before overwrite

    // ---- Phase 5: merged zero+scatter burst write (one visit per line) ----
    #pragma unroll 1
    for (int rr=0; rr<16; ++rr) {
        const int row = rr*4 + wv;          // one row per wave
        float pv[8]; int pi[8];
        #pragma unroll
        for (int s=0;s<8;s++) {             // broadcast LDS reads
            pv[s] = final8[row*16 + s*2];
            pi[s] = __float_as_int(final8[row*16 + s*2 + 1]);
        }
        float* orow = out + obase + (size_t)row*NPOOL;
        #pragma unroll
        for (int j=0;j<8;j++) {
            const int f4i = j*64 + lane;
            float v0=0.f, v1=0.f, v2=0.f, v3=0.f;
            #pragma unroll
            for (int s=0;s<8;s++) {
                const int d = pi[s] - f4i*4;
                v0 = (d==0) ? pv[s] : v0;
                v1 = (d==1) ? pv[s] : v1;
                v2 = (d==2) ? pv[s] : v2;
                v3 = (d==3) ? pv[s] : v3;
            }
            *(float4*)&orow[f4i*4] = make_float4(v0,v1,v2,v3);
        }
    }
}

extern "C" void kernel_launch(void* const* d_in, const int* in_sizes, int n_in,
                              void* d_out, int out_size, void* d_ws, size_t ws_size,
                              hipStream_t stream) {
    (void)in_sizes; (void)n_in; (void)d_ws; (void)ws_size; (void)out_size;
    const float* x   = (const float*)d_in[0];
    const float* Wm  = (const float*)d_in[1];
    const float* bb  = (const float*)d_in[2];
    const float* emb = (const float*)d_in[3];
    float* out = (float*)d_out;
    dim3 grid(NROWS / TILE_M, HEADS);
    proj_k <<<grid, dim3(256), 0, stream>>>(x, Wm, bb, out);
    route_k<<<grid, dim3(256), 0, stream>>>(emb, out);
}

// Round 6
// 999.187 us; speedup vs baseline: 15.2125x; 2.3928x over previous
//
#include <hip/hip_runtime.h>
#include <hip/hip_bf16.h>
#include <math.h>

#define HEADS   6
#define DMODEL  1024
#define NPROJ   384
#define DSP     64
#define NPOOL   2048
#define NROWS   8192
#define TILE_M  64
#define KT      64
#define KEEP    16

#define LOG2E_F 1.44269504088896340f
#define LOG2E_D 1.4426950408889634
#define C2      14.4269504088896340f   /* 10*log2(e); |logit| provably < 10 */

#define NINF (-__builtin_inff())
#define IMAX 0x7fffffff

typedef __attribute__((ext_vector_type(8))) short short8;
typedef __attribute__((ext_vector_type(4))) float f32x4;

__device__ __forceinline__ bool bet_f(float v, int vi, float w, int wi) {
    return (v > w) || (v == w && vi < wi);
}
__device__ __forceinline__ bool bet_d(double v, int vi, double w, int wi) {
    return (v > w) || (v == w && vi < wi);
}
__device__ __forceinline__ unsigned short f2bf(float f) {   // RNE, no NaN inputs
    unsigned int u = __float_as_uint(f);
    return (unsigned short)((u + 0x7fffu + ((u >> 16) & 1u)) >> 16);
}
__device__ __forceinline__ float bf2f(unsigned short s) {
    return __uint_as_float(((unsigned int)s) << 16);
}
__device__ __forceinline__ unsigned int packbf2(float a, float b) {
    return (unsigned int)f2bf(a) | ((unsigned int)f2bf(b) << 16);
}

// ---------- named-scalar top-8 list machinery (NO private arrays => no scratch) ----------
#define DECL8(r) \
    float tv##r##0=NINF,tv##r##1=NINF,tv##r##2=NINF,tv##r##3=NINF, \
          tv##r##4=NINF,tv##r##5=NINF,tv##r##6=NINF,tv##r##7=NINF; \
    int   ti##r##0=IMAX,ti##r##1=IMAX,ti##r##2=IMAX,ti##r##3=IMAX, \
          ti##r##4=IMAX,ti##r##5=IMAX,ti##r##6=IMAX,ti##r##7=IMAX;

#define CSW8(r,hi,lo) { \
    const bool sw_ = bet_f(tv##r##lo,ti##r##lo,tv##r##hi,ti##r##hi); \
    const float tf_ = tv##r##hi; const int tj_ = ti##r##hi; \
    tv##r##hi = sw_?tv##r##lo:tv##r##hi; ti##r##hi = sw_?ti##r##lo:ti##r##hi; \
    tv##r##lo = sw_?tf_:tv##r##lo;       ti##r##lo = sw_?tj_:ti##r##lo; }

#define INS8(r,W,CI) \
    if (bet_f(W,CI,tv##r##7,ti##r##7)) { \
        tv##r##7=(W); ti##r##7=(CI); \
        CSW8(r,6,7) CSW8(r,5,6) CSW8(r,4,5) CSW8(r,3,4) \
        CSW8(r,2,3) CSW8(r,1,2) CSW8(r,0,1) }

// in-wave 16-lane tournament: extract global top-16 of one row from 16 sorted 8-lists.
// round-k winner recorded by lane m==k; winner lane shifts its list down.
#define TOURN(r, ROW) { \
    int slot_ = IMAX; \
    for (int k_=0;k_<16;++k_) { \
        float v_ = tv##r##0; int ix_ = ti##r##0; \
        { float ov=__shfl_xor(v_,1,64); int oj=__shfl_xor(ix_,1,64); if (bet_f(ov,oj,v_,ix_)){v_=ov;ix_=oj;} } \
        { float ov=__shfl_xor(v_,2,64); int oj=__shfl_xor(ix_,2,64); if (bet_f(ov,oj,v_,ix_)){v_=ov;ix_=oj;} } \
        { float ov=__shfl_xor(v_,4,64); int oj=__shfl_xor(ix_,4,64); if (bet_f(ov,oj,v_,ix_)){v_=ov;ix_=oj;} } \
        { float ov=__shfl_xor(v_,8,64); int oj=__shfl_xor(ix_,8,64); if (bet_f(ov,oj,v_,ix_)){v_=ov;ix_=oj;} } \
        const bool won_ = (ix_ == ti##r##0); \
        tv##r##0 = won_?tv##r##1:tv##r##0; ti##r##0 = won_?ti##r##1:ti##r##0; \
        tv##r##1 = won_?tv##r##2:tv##r##1; ti##r##1 = won_?ti##r##2:ti##r##1; \
        tv##r##2 = won_?tv##r##3:tv##r##2; ti##r##2 = won_?ti##r##3:ti##r##2; \
        tv##r##3 = won_?tv##r##4:tv##r##3; ti##r##3 = won_?ti##r##4:ti##r##3; \
        tv##r##4 = won_?tv##r##5:tv##r##4; ti##r##4 = won_?ti##r##5:ti##r##4; \
        tv##r##5 = won_?tv##r##6:tv##r##5; ti##r##5 = won_?ti##r##6:ti##r##5; \
        tv##r##6 = won_?tv##r##7:tv##r##6; ti##r##6 = won_?ti##r##7:ti##r##6; \
        tv##r##7 = won_?NINF:tv##r##7;     ti##r##7 = won_?IMAX:ti##r##7; \
        slot_ = (m==k_)?ix_:slot_; \
    } \
    ridx16[(ROW)*16 + m] = slot_; }

// double-precision named top-8 (phase 4)
#define CSWD(hi,lo) { \
    const bool sw_ = bet_d(dv##lo,di##lo,dv##hi,di##hi); \
    const double td_ = dv##hi; const int tj_ = di##hi; \
    dv##hi = sw_?dv##lo:dv##hi; di##hi = sw_?di##lo:di##hi; \
    dv##lo = sw_?td_:dv##lo;    di##lo = sw_?tj_:di##lo; }

#define INS8D(W,CI) \
    if (bet_d(W,CI,dv7,di7)) { dv7=(W); di7=(CI); \
        CSWD(6,7) CSWD(5,6) CSWD(4,5) CSWD(3,4) CSWD(2,3) CSWD(1,2) CSWD(0,1) }

// ======================= Kernel 1: fp64 projection =======================
// h written into the block's own output region:
//   h_hi f32 [64][64] at out+obase, h_lo bf16 [64][64] at out+obase+4096 floats.
#define PJROW(i) \
    a##i##0 = fma(xd##i, wd0, a##i##0); a##i##1 = fma(xd##i, wd1, a##i##1); \
    a##i##2 = fma(xd##i, wd2, a##i##2); a##i##3 = fma(xd##i, wd3, a##i##3);

#define EPI(i) { \
    const double v0_=a##i##0+bj0, v1_=a##i##1+bj1, v2_=a##i##2+bj2, v3_=a##i##3+bj3; \
    float4 hv; ushort4 lv; \
    hv.x=(float)v0_; hv.y=(float)v1_; hv.z=(float)v2_; hv.w=(float)v3_; \
    lv.x=f2bf((float)(v0_-(double)hv.x)); lv.y=f2bf((float)(v1_-(double)hv.y)); \
    lv.z=f2bf((float)(v2_-(double)hv.z)); lv.w=f2bf((float)(v3_-(double)hv.w)); \
    *(float4*) &hhi[(size_t)(rg*4+i)*64 + cg*4] = hv; \
    *(ushort4*)&hlo[(size_t)(rg*4+i)*64 + cg*4] = lv; }

__global__ __launch_bounds__(256, 3)
void proj_k(const float* __restrict__ x, const float* __restrict__ Wm,
            const float* __restrict__ bb, float* __restrict__ out)
{
    __shared__ __align__(16) float x_t[64*68];   // [k][row]
    __shared__ __align__(16) float w_t[64*68];   // [k][col]

    const int t    = threadIdx.x;
    const int cg   = t & 15;
    const int rg   = t >> 4;
    const int head = blockIdx.y;
    const int row0 = blockIdx.x * TILE_M;
    const size_t obase = ((size_t)head*NROWS + row0) * (size_t)NPOOL;

    double a00=0,a01=0,a02=0,a03=0, a10=0,a11=0,a12=0,a13=0,
           a20=0,a21=0,a22=0,a23=0, a30=0,a31=0,a32=0,a33=0;

    const int xr = t >> 2;        // 0..63 row
    const int xq = t & 3;         // k quarter (16 k's)
    const int wr = t >> 4;        // 0..15 base k-row for W
    const float* wbase = Wm + head*64 + cg*4;

    float4 xv0,xv1,xv2,xv3, wv0,wv1,wv2,wv3;
    {
        const float* xsrc = x + (size_t)(row0+xr)*DMODEL + xq*16;
        xv0 = *(const float4*)(xsrc);     xv1 = *(const float4*)(xsrc + 4);
        xv2 = *(const float4*)(xsrc + 8); xv3 = *(const float4*)(xsrc + 12);
        wv0 = *(const float4*)(wbase + (size_t)(wr     )*NPROJ);
        wv1 = *(const float4*)(wbase + (size_t)(wr + 16)*NPROJ);
        wv2 = *(const float4*)(wbase + (size_t)(wr + 32)*NPROJ);
        wv3 = *(const float4*)(wbase + (size_t)(wr + 48)*NPROJ);
    }

    for (int kk = 0; kk < DMODEL; kk += KT) {
        __syncthreads();   // prev tile's LDS reads done
        {
            const int k0 = xq*16;
            x_t[(k0+ 0)*68+xr]=xv0.x; x_t[(k0+ 1)*68+xr]=xv0.y; x_t[(k0+ 2)*68+xr]=xv0.z; x_t[(k0+ 3)*68+xr]=xv0.w;
            x_t[(k0+ 4)*68+xr]=xv1.x; x_t[(k0+ 5)*68+xr]=xv1.y; x_t[(k0+ 6)*68+xr]=xv1.z; x_t[(k0+ 7)*68+xr]=xv1.w;
            x_t[(k0+ 8)*68+xr]=xv2.x; x_t[(k0+ 9)*68+xr]=xv2.y; x_t[(k0+10)*68+xr]=xv2.z; x_t[(k0+11)*68+xr]=xv2.w;
            x_t[(k0+12)*68+xr]=xv3.x; x_t[(k0+13)*68+xr]=xv3.y; x_t[(k0+14)*68+xr]=xv3.z; x_t[(k0+15)*68+xr]=xv3.w;
            *(float4*)&w_t[(wr     )*68 + cg*4] = wv0;
            *(float4*)&w_t[(wr + 16)*68 + cg*4] = wv1;
            *(float4*)&w_t[(wr + 32)*68 + cg*4] = wv2;
            *(float4*)&w_t[(wr + 48)*68 + cg*4] = wv3;
        }
        __syncthreads();
        if (kk + KT < DMODEL) {   // prefetch next tile
            const float* xsrc = x + (size_t)(row0+xr)*DMODEL + (kk+KT) + xq*16;
            xv0 = *(const float4*)(xsrc);     xv1 = *(const float4*)(xsrc + 4);
            xv2 = *(const float4*)(xsrc + 8); xv3 = *(const float4*)(xsrc + 12);
            wv0 = *(const float4*)(wbase + (size_t)(kk+KT + wr     )*NPROJ);
            wv1 = *(const float4*)(wbase + (size_t)(kk+KT + wr + 16)*NPROJ);
            wv2 = *(const float4*)(wbase + (size_t)(kk+KT + wr + 32)*NPROJ);
            wv3 = *(const float4*)(wbase + (size_t)(kk+KT + wr + 48)*NPROJ);
        }
        #pragma unroll 4
        for (int k=0;k<KT;k++) {
            const float4 xf = *(const float4*)&x_t[k*68 + rg*4];
            const float4 wf = *(const float4*)&w_t[k*68 + cg*4];
            const double xd0=(double)xf.x, xd1=(double)xf.y, xd2=(double)xf.z, xd3=(double)xf.w;
            const double wd0=(double)wf.x, wd1=(double)wf.y, wd2=(double)wf.z, wd3=(double)wf.w;
            PJROW(0) PJROW(1) PJROW(2) PJROW(3)
        }
    }

    float*  hhi = out + obase;                       // [64][64] f32
    ushort* hlo = (ushort*)(out + obase + 4096);     // [64][64] bf16
    const double bj0=(double)bb[head*64+cg*4+0], bj1=(double)bb[head*64+cg*4+1];
    const double bj2=(double)bb[head*64+cg*4+2], bj3=(double)bb[head*64+cg*4+3];
    EPI(0) EPI(1) EPI(2) EPI(3)
}

// ======================= Kernel 2: router =======================
__global__ __launch_bounds__(256, 3)
void route_k(const float* __restrict__ emb, float* __restrict__ out)
{
    __shared__ int    ridx16[64*16];                 // 4096 B
    __shared__ float  zbuf[64];
    __shared__ double rv[64*17];                     // 8704 B
    __shared__ __align__(8) float final8[64*16];     // 4096 B

    const int t    = threadIdx.x;
    const int lane = t & 63, wv = t >> 6;
    const int m    = lane & 15, q = lane >> 4;
    const int head = blockIdx.y;
    const int row0 = blockIdx.x * TILE_M;
    const size_t obase = ((size_t)head*NROWS + row0) * (size_t)NPOOL;

    int psel = 0;                 // pools: [fqk,fqk,fv,rqk,rqk,rv]
    if (head >= 2) psel = 1;
    if (head >= 3) psel = 2;
    if (head >= 5) psel = 3;
    const float* epool = emb + (size_t)psel * NPOOL * DSP;

    // ---- A fragments: h rows of this wave, bf16, from h_hi scratch ----
    union FragU { unsigned int u[4]; short8 s; };
    FragU A0, A1;
    {
        const float* hr = out + obase + (size_t)(wv*16 + m)*64 + q*8;
        const float4 a0 = *(const float4*)(hr);
        const float4 a1 = *(const float4*)(hr + 4);
        const float4 a2 = *(const float4*)(hr + 32);
        const float4 a3 = *(const float4*)(hr + 36);
        A0.u[0]=packbf2(a0.x,a0.y); A0.u[1]=packbf2(a0.z,a0.w);
        A0.u[2]=packbf2(a1.x,a1.y); A0.u[3]=packbf2(a1.z,a1.w);
        A1.u[0]=packbf2(a2.x,a2.y); A1.u[1]=packbf2(a2.z,a2.w);
        A1.u[2]=packbf2(a3.x,a3.y); A1.u[3]=packbf2(a3.z,a3.w);
    }

    // ---- Phase 1: MFMA logits, Z, per-lane top-8 in NAMED scalars ----
    DECL8(0) DECL8(1) DECL8(2) DECL8(3)
    float zacc0=0.f, zacc1=0.f, zacc2=0.f, zacc3=0.f;

    #pragma unroll 1
    for (int it=0; it<128; ++it) {
        const int cidx = it*16 + m;                 // e row this lane needs
        const float* er = epool + (size_t)cidx*DSP + q*8;
        const float4 e0 = *(const float4*)(er);
        const float4 e1 = *(const float4*)(er + 4);
        const float4 e2 = *(const float4*)(er + 32);
        const float4 e3 = *(const float4*)(er + 36);
        float ss = e0.x*e0.x + e0.y*e0.y + e0.z*e0.z + e0.w*e0.w
                 + e1.x*e1.x + e1.y*e1.y + e1.z*e1.z + e1.w*e1.w
                 + e2.x*e2.x + e2.y*e2.y + e2.z*e2.z + e2.w*e2.w
                 + e3.x*e3.x + e3.y*e3.y + e3.z*e3.z + e3.w*e3.w;
        ss += __shfl_xor(ss, 16, 64);
        ss += __shfl_xor(ss, 32, 64);
        const float inv = LOG2E_F / fmaxf(sqrtf(ss), 1e-12f);
        FragU B0, B1;
        B0.u[0]=packbf2(e0.x*inv, e0.y*inv); B0.u[1]=packbf2(e0.z*inv, e0.w*inv);
        B0.u[2]=packbf2(e1.x*inv, e1.y*inv); B0.u[3]=packbf2(e1.z*inv, e1.w*inv);
        B1.u[0]=packbf2(e2.x*inv, e2.y*inv); B1.u[1]=packbf2(e2.z*inv, e2.w*inv);
        B1.u[2]=packbf2(e3.x*inv, e3.y*inv); B1.u[3]=packbf2(e3.z*inv, e3.w*inv);

        f32x4 cc = {0.f,0.f,0.f,0.f};
        cc = __builtin_amdgcn_mfma_f32_16x16x32_bf16(A0.s, B0.s, cc, 0, 0, 0);
        cc = __builtin_amdgcn_mfma_f32_16x16x32_bf16(A1.s, B1.s, cc, 0, 0, 0);

        { const float w_ = cc[0]; zacc0 += exp2f(w_ - C2); INS8(0, w_, cidx) }
        { const float w_ = cc[1]; zacc1 += exp2f(w_ - C2); INS8(1, w_, cidx) }
        { const float w_ = cc[2]; zacc2 += exp2f(w_ - C2); INS8(2, w_, cidx) }
        { const float w_ = cc[3]; zacc3 += exp2f(w_ - C2); INS8(3, w_, cidx) }
    }

    // ---- Z reduce over the 16 col-lanes of each row ----
    { float z=zacc0; z+=__shfl_xor(z,1,64); z+=__shfl_xor(z,2,64); z+=__shfl_xor(z,4,64); z+=__shfl_xor(z,8,64); if(m==0) zbuf[wv*16+q*4+0]=z; }
    { float z=zacc1; z+=__shfl_xor(z,1,64); z+=__shfl_xor(z,2,64); z+=__shfl_xor(z,4,64); z+=__shfl_xor(z,8,64); if(m==0) zbuf[wv*16+q*4+1]=z; }
    { float z=zacc2; z+=__shfl_xor(z,1,64); z+=__shfl_xor(z,2,64); z+=__shfl_xor(z,4,64); z+=__shfl_xor(z,8,64); if(m==0) zbuf[wv*16+q*4+2]=z; }
    { float z=zacc3; z+=__shfl_xor(z,1,64); z+=__shfl_xor(z,2,64); z+=__shfl_xor(z,4,64); z+=__shfl_xor(z,8,64); if(m==0) zbuf[wv*16+q*4+3]=z; }

    // ---- in-wave tournament: per-row top-16 into ridx16 (sorted desc) ----
    TOURN(0, wv*16 + q*4 + 0)
    TOURN(1, wv*16 + q*4 + 1)
    TOURN(2, wv*16 + q*4 + 2)
    TOURN(3, wv*16 + q*4 + 3)
    __syncthreads();

    // ---- Phase 3: fp64 rescore of the 16 candidates per row ----
    {
        const int row = t >> 2, q4 = t & 3;   // 4 candidates per thread
        const int ix0 = ridx16[row*16 + q4*4 + 0];
        const int ix1 = ridx16[row*16 + q4*4 + 1];
        const int ix2 = ridx16[row*16 + q4*4 + 2];
        const int ix3 = ridx16[row*16 + q4*4 + 3];
        const float* ep0 = epool + (size_t)ix0*DSP;
        const float* ep1 = epool + (size_t)ix1*DSP;
        const float* ep2 = epool + (size_t)ix2*DSP;
        const float* ep3 = epool + (size_t)ix3*DSP;
        const float*  hhr = out + obase + (size_t)row*64;
        const ushort* hlr = (const ushort*)(out + obase + 4096) + (size_t)row*64;
        double nn0=0,nn1=0,nn2=0,nn3=0, dd0=0,dd1=0,dd2=0,dd3=0;
        #pragma unroll 1
        for (int k4=0; k4<DSP; k4+=4) {
            const double h0 = (double)hhr[k4+0] + (double)bf2f(hlr[k4+0]);
            const double h1 = (double)hhr[k4+1] + (double)bf2f(hlr[k4+1]);
            const double h2 = (double)hhr[k4+2] + (double)bf2f(hlr[k4+2]);
            const double h3 = (double)hhr[k4+3] + (double)bf2f(hlr[k4+3]);
            #define RS(s) { const float4 e_ = *(const float4*)(ep##s + k4); \
                const double e0_=(double)e_.x, e1_=(double)e_.y, e2_=(double)e_.z, e3_=(double)e_.w; \
                nn##s += e0_*e0_ + e1_*e1_ + e2_*e2_ + e3_*e3_; \
                dd##s += h0*e0_ + h1*e1_ + h2*e2_ + h3*e3_; }
            RS(0) RS(1) RS(2) RS(3)
            #undef RS
        }
        rv[row*17 + q4*4 + 0] = dd0 / fmax(sqrt(nn0), 1e-12);
        rv[row*17 + q4*4 + 1] = dd1 / fmax(sqrt(nn1), 1e-12);
        rv[row*17 + q4*4 + 2] = dd2 / fmax(sqrt(nn2), 1e-12);
        rv[row*17 + q4*4 + 3] = dd3 / fmax(sqrt(nn3), 1e-12);
    }
    __syncthreads();

    // ---- Phase 4: fp64 top-8 select (named scalars), normalize, stash in LDS ----
    if (t < 64) {
        const float Zg = zbuf[t];
        double dv0=-INFINITY,dv1=-INFINITY,dv2=-INFINITY,dv3=-INFINITY,
               dv4=-INFINITY,dv5=-INFINITY,dv6=-INFINITY,dv7=-INFINITY;
        int    di0=IMAX,di1=IMAX,di2=IMAX,di3=IMAX,di4=IMAX,di5=IMAX,di6=IMAX,di7=IMAX;
        #pragma unroll 1
        for (int s=0;s<KEEP;s++) {
            const double v_  = rv[t*17 + s];
            const int    ix_ = ridx16[t*16 + s];
            INS8D(v_, ix_)
        }
        float denom = 1e-8f * Zg;
        const float ov0 = exp2f((float)(dv0*LOG2E_D) - C2); denom += ov0;
        const float ov1 = exp2f((float)(dv1*LOG2E_D) - C2); denom += ov1;
        const float ov2 = exp2f((float)(dv2*LOG2E_D) - C2); denom += ov2;
        const float ov3 = exp2f((float)(dv3*LOG2E_D) - C2); denom += ov3;
        const float ov4 = exp2f((float)(dv4*LOG2E_D) - C2); denom += ov4;
        const float ov5 = exp2f((float)(dv5*LOG2E_D) - C2); denom += ov5;
        const float ov6 = exp2f((float)(dv6*LOG2E_D) - C2); denom += ov6;
        const float ov7 = exp2f((float)(dv7*LOG2E_D) - C2); denom += ov7;
        const float rd = 1.0f / denom;
        float2 p;
        p.x=ov0*rd; p.y=__int_as_float(di0); *(float2*)&final8[t*16 +  0] = p;
        p.x=ov1*rd; p.y=__int_as_float(di1); *(float2*)&final8[t*16 +  2] = p;
        p.x=ov2*rd; p.y=__int_as_float(di2); *(float2*)&final8[t*16 +  4] = p;
        p.x=ov3*rd; p.y=__int_as_float(di3); *(float2*)&final8[t*16 +  6] = p;
        p.x=ov4*rd; p.y=__int_as_float(di4); *(float2*)&final8[t*16 +  8] = p;
        p.x=ov5*rd; p.y=__int_as_float(di5); *(float2*)&final8[t*16 + 10] = p;
        p.x=ov6*rd; p.y=__int_as_float(di6); *(float2*)&final8[t*16 + 12] = p;
        p.x=ov7*rd; p.y=__int_as_float(di7); *(float2*)&final8[t*16 + 14] = p;
    }
    __syncthreads();   // drains rescore loads + final8 stores before overwrite

    // ---- Phase 5: merged zero+scatter burst write (one visit per line) ----
    #pragma unroll 1
    for (int rr=0; rr<16; ++rr) {
        const int row = rr*4 + wv;          // one row per wave
        const float* fb = &final8[row*16];  // broadcast LDS reads
        const float pv0=fb[ 0]; const int pi0=__float_as_int(fb[ 1]);
        const float pv1=fb[ 2]; const int pi1=__float_as_int(fb[ 3]);
        const float pv2=fb[ 4]; const int pi2=__float_as_int(fb[ 5]);
        const float pv3=fb[ 6]; const int pi3=__float_as_int(fb[ 7]);
        const float pv4=fb[ 8]; const int pi4=__float_as_int(fb[ 9]);
        const float pv5=fb[10]; const int pi5=__float_as_int(fb[11]);
        const float pv6=fb[12]; const int pi6=__float_as_int(fb[13]);
        const float pv7=fb[14]; const int pi7=__float_as_int(fb[15]);
        float* orow = out + obase + (size_t)row*NPOOL;
        #pragma unroll
        for (int j=0;j<8;j++) {
            const int base4 = (j*64 + lane)*4;
            float v0=0.f, v1=0.f, v2=0.f, v3=0.f;
            #define SCAT(s) { const int d_ = pi##s - base4; \
                v0=(d_==0)?pv##s:v0; v1=(d_==1)?pv##s:v1; \
                v2=(d_==2)?pv##s:v2; v3=(d_==3)?pv##s:v3; }
            SCAT(0) SCAT(1) SCAT(2) SCAT(3) SCAT(4) SCAT(5) SCAT(6) SCAT(7)
            #undef SCAT
            *(float4*)&orow[base4] = make_float4(v0,v1,v2,v3);
        }
    }
}

extern "C" void kernel_launch(void* const* d_in, const int* in_sizes, int n_in,
                              void* d_out, int out_size, void* d_ws, size_t ws_size,
                              hipStream_t stream) {
    (void)in_sizes; (void)n_in; (void)d_ws; (void)ws_size; (void)out_size;
    const float* x   = (const float*)d_in[0];
    const float* Wm  = (const float*)d_in[1];
    const float* bb  = (const float*)d_in[2];
    const float* emb = (const float*)d_in[3];
    float* out = (float*)d_out;
    dim3 grid(NROWS / TILE_M, HEADS);
    proj_k <<<grid, dim3(256), 0, stream>>>(x, Wm, bb, out);
    route_k<<<grid, dim3(256), 0, stream>>>(emb, out);
}

// Round 8
// 927.481 us; speedup vs baseline: 16.3886x; 1.0773x over previous
//
#include <hip/hip_runtime.h>
#include <hip/hip_bf16.h>
#include <math.h>

#define HEADS   6
#define DMODEL  1024
#define NPROJ   384
#define DSP     64
#define NPOOL   2048
#define NROWS   8192
#define TILE_M  64
#define KT      64
#define KEEP    16

#define LOG2E_F 1.44269504088896340f
#define LOG2E_D 1.4426950408889634
#define C2      14.4269504088896340f   /* 10*log2(e); |logit| provably < 10 */

#define NINF (-__builtin_inff())
#define IMAX 0x7fffffff

typedef __attribute__((ext_vector_type(8))) short  short8;
typedef __attribute__((ext_vector_type(4))) float  f32x4;

__device__ __forceinline__ bool bet_f(float v, int vi, float w, int wi) {
    return (v > w) || (v == w && vi < wi);
}
__device__ __forceinline__ bool bet_d(double v, int vi, double w, int wi) {
    return (v > w) || (v == w && vi < wi);
}
__device__ __forceinline__ unsigned short f2bf(float f) {   // RNE, no NaN inputs
    unsigned int u = __float_as_uint(f);
    return (unsigned short)((u + 0x7fffu + ((u >> 16) & 1u)) >> 16);
}
__device__ __forceinline__ float bf2f(unsigned short s) {
    return __uint_as_float(((unsigned int)s) << 16);
}
__device__ __forceinline__ unsigned int packbf2(float a, float b) {
    return (unsigned int)f2bf(a) | ((unsigned int)f2bf(b) << 16);
}

// ---------- named-scalar top-8 list machinery (NO private arrays => no scratch) ----------
#define DECL8(r) \
    float tv##r##0=NINF,tv##r##1=NINF,tv##r##2=NINF,tv##r##3=NINF, \
          tv##r##4=NINF,tv##r##5=NINF,tv##r##6=NINF,tv##r##7=NINF; \
    int   ti##r##0=IMAX,ti##r##1=IMAX,ti##r##2=IMAX,ti##r##3=IMAX, \
          ti##r##4=IMAX,ti##r##5=IMAX,ti##r##6=IMAX,ti##r##7=IMAX;

#define CSW8(r,hi,lo) { \
    const bool sw_ = bet_f(tv##r##lo,ti##r##lo,tv##r##hi,ti##r##hi); \
    const float tf_ = tv##r##hi; const int tj_ = ti##r##hi; \
    tv##r##hi = sw_?tv##r##lo:tv##r##hi; ti##r##hi = sw_?ti##r##lo:ti##r##hi; \
    tv##r##lo = sw_?tf_:tv##r##lo;       ti##r##lo = sw_?tj_:ti##r##lo; }

#define INS8(r,W,CI) \
    if (bet_f(W,CI,tv##r##7,ti##r##7)) { \
        tv##r##7=(W); ti##r##7=(CI); \
        CSW8(r,6,7) CSW8(r,5,6) CSW8(r,4,5) CSW8(r,3,4) \
        CSW8(r,2,3) CSW8(r,1,2) CSW8(r,0,1) }

// in-wave 16-lane tournament: global top-16 of one row from 16 sorted 8-lists.
#define TOURN(r, ROW) { \
    int slot_ = IMAX; \
    for (int k_=0;k_<16;++k_) { \
        float v_ = tv##r##0; int ix_ = ti##r##0; \
        { float ov=__shfl_xor(v_,1,64); int oj=__shfl_xor(ix_,1,64); if (bet_f(ov,oj,v_,ix_)){v_=ov;ix_=oj;} } \
        { float ov=__shfl_xor(v_,2,64); int oj=__shfl_xor(ix_,2,64); if (bet_f(ov,oj,v_,ix_)){v_=ov;ix_=oj;} } \
        { float ov=__shfl_xor(v_,4,64); int oj=__shfl_xor(ix_,4,64); if (bet_f(ov,oj,v_,ix_)){v_=ov;ix_=oj;} } \
        { float ov=__shfl_xor(v_,8,64); int oj=__shfl_xor(ix_,8,64); if (bet_f(ov,oj,v_,ix_)){v_=ov;ix_=oj;} } \
        const bool won_ = (ix_ == ti##r##0); \
        tv##r##0 = won_?tv##r##1:tv##r##0; ti##r##0 = won_?ti##r##1:ti##r##0; \
        tv##r##1 = won_?tv##r##2:tv##r##1; ti##r##1 = won_?ti##r##2:ti##r##1; \
        tv##r##2 = won_?tv##r##3:tv##r##2; ti##r##2 = won_?ti##r##3:ti##r##2; \
        tv##r##3 = won_?tv##r##4:tv##r##3; ti##r##3 = won_?ti##r##4:ti##r##3; \
        tv##r##4 = won_?tv##r##5:tv##r##4; ti##r##4 = won_?ti##r##5:ti##r##4; \
        tv##r##5 = won_?tv##r##6:tv##r##5; ti##r##5 = won_?ti##r##6:ti##r##5; \
        tv##r##6 = won_?tv##r##7:tv##r##6; ti##r##6 = won_?ti##r##7:ti##r##6; \
        tv##r##7 = won_?NINF:tv##r##7;     ti##r##7 = won_?IMAX:ti##r##7; \
        slot_ = (m==k_)?ix_:slot_; \
    } \
    ridx16[(ROW)*16 + m] = slot_; }

// double-precision named top-8 (phase 4)
#define CSWD(hi,lo) { \
    const bool sw_ = bet_d(dv##lo,di##lo,dv##hi,di##hi); \
    const double td_ = dv##hi; const int tj_ = di##hi; \
    dv##hi = sw_?dv##lo:dv##hi; di##hi = sw_?di##lo:di##hi; \
    dv##lo = sw_?td_:dv##lo;    di##lo = sw_?tj_:di##lo; }

#define INS8D(W,CI) \
    if (bet_d(W,CI,dv7,di7)) { dv7=(W); di7=(CI); \
        CSWD(6,7) CSWD(5,6) CSWD(4,5) CSWD(3,4) CSWD(2,3) CSWD(1,2) CSWD(0,1) }

// ======================= Kernel 0: pool prep =======================
// Normalize pools 0..3 of emb (8192 rows), fold in LOG2E, pack bf16 -> d_ws.
__global__ __launch_bounds__(256)
void prep_k(const float* __restrict__ emb, ushort* __restrict__ ebf)
{
    const int row = blockIdx.x*256 + threadIdx.x;   // 0..8191 (pools fqk,fv,rqk,rv)
    const float* src = emb + (size_t)row*DSP;
    float ss = 0.f;
    #pragma unroll
    for (int g=0; g<16; ++g) {
        const float4 v = *(const float4*)(src + g*4);
        ss += v.x*v.x + v.y*v.y + v.z*v.z + v.w*v.w;
    }
    const float inv = LOG2E_F / fmaxf(sqrtf(ss), 1e-12f);
    ushort* dst = ebf + (size_t)row*DSP;
    #pragma unroll
    for (int g=0; g<8; ++g) {
        const float4 a = *(const float4*)(src + g*8);
        const float4 b = *(const float4*)(src + g*8 + 4);
        uint4 o;
        o.x = packbf2(a.x*inv, a.y*inv);
        o.y = packbf2(a.z*inv, a.w*inv);
        o.z = packbf2(b.x*inv, b.y*inv);
        o.w = packbf2(b.z*inv, b.w*inv);
        *(uint4*)(dst + g*8) = o;
    }
}

// ======================= Kernel 1: fp64 VALU projection (R6-verified) =======================
// h written into the block's own output region:
//   h_hi f32 [64][64] at out+obase, h_lo bf16 [64][64] at out+obase+4096 floats.
#define PJROW(i) \
    a##i##0 = fma(xd##i, wd0, a##i##0); a##i##1 = fma(xd##i, wd1, a##i##1); \
    a##i##2 = fma(xd##i, wd2, a##i##2); a##i##3 = fma(xd##i, wd3, a##i##3);

#define EPI(i) { \
    const double v0_=a##i##0+bj0, v1_=a##i##1+bj1, v2_=a##i##2+bj2, v3_=a##i##3+bj3; \
    float4 hv; ushort4 lv; \
    hv.x=(float)v0_; hv.y=(float)v1_; hv.z=(float)v2_; hv.w=(float)v3_; \
    lv.x=f2bf((float)(v0_-(double)hv.x)); lv.y=f2bf((float)(v1_-(double)hv.y)); \
    lv.z=f2bf((float)(v2_-(double)hv.z)); lv.w=f2bf((float)(v3_-(double)hv.w)); \
    *(float4*) &hhi[(size_t)(rg*4+i)*64 + cg*4] = hv; \
    *(ushort4*)&hlo[(size_t)(rg*4+i)*64 + cg*4] = lv; }

__global__ __launch_bounds__(256, 3)
void proj_k(const float* __restrict__ x, const float* __restrict__ Wm,
            const float* __restrict__ bb, float* __restrict__ out)
{
    __shared__ __align__(16) float x_t[64*68];   // [k][row]
    __shared__ __align__(16) float w_t[64*68];   // [k][col]

    const int t    = threadIdx.x;
    const int cg   = t & 15;
    const int rg   = t >> 4;
    const int head = blockIdx.y;
    const int row0 = blockIdx.x * TILE_M;
    const size_t obase = ((size_t)head*NROWS + row0) * (size_t)NPOOL;

    double a00=0,a01=0,a02=0,a03=0, a10=0,a11=0,a12=0,a13=0,
           a20=0,a21=0,a22=0,a23=0, a30=0,a31=0,a32=0,a33=0;

    const int xr = t >> 2;        // 0..63 row
    const int xq = t & 3;         // k quarter (16 k's)
    const int wr = t >> 4;        // 0..15 base k-row for W
    const float* wbase = Wm + head*64 + cg*4;

    float4 xv0,xv1,xv2,xv3, wv0,wv1,wv2,wv3;
    {
        const float* xsrc = x + (size_t)(row0+xr)*DMODEL + xq*16;
        xv0 = *(const float4*)(xsrc);     xv1 = *(const float4*)(xsrc + 4);
        xv2 = *(const float4*)(xsrc + 8); xv3 = *(const float4*)(xsrc + 12);
        wv0 = *(const float4*)(wbase + (size_t)(wr     )*NPROJ);
        wv1 = *(const float4*)(wbase + (size_t)(wr + 16)*NPROJ);
        wv2 = *(const float4*)(wbase + (size_t)(wr + 32)*NPROJ);
        wv3 = *(const float4*)(wbase + (size_t)(wr + 48)*NPROJ);
    }

    for (int kk = 0; kk < DMODEL; kk += KT) {
        __syncthreads();   // prev tile's LDS reads done
        {
            const int k0 = xq*16;
            x_t[(k0+ 0)*68+xr]=xv0.x; x_t[(k0+ 1)*68+xr]=xv0.y; x_t[(k0+ 2)*68+xr]=xv0.z; x_t[(k0+ 3)*68+xr]=xv0.w;
            x_t[(k0+ 4)*68+xr]=xv1.x; x_t[(k0+ 5)*68+xr]=xv1.y; x_t[(k0+ 6)*68+xr]=xv1.z; x_t[(k0+ 7)*68+xr]=xv1.w;
            x_t[(k0+ 8)*68+xr]=xv2.x; x_t[(k0+ 9)*68+xr]=xv2.y; x_t[(k0+10)*68+xr]=xv2.z; x_t[(k0+11)*68+xr]=xv2.w;
            x_t[(k0+12)*68+xr]=xv3.x; x_t[(k0+13)*68+xr]=xv3.y; x_t[(k0+14)*68+xr]=xv3.z; x_t[(k0+15)*68+xr]=xv3.w;
            *(float4*)&w_t[(wr     )*68 + cg*4] = wv0;
            *(float4*)&w_t[(wr + 16)*68 + cg*4] = wv1;
            *(float4*)&w_t[(wr + 32)*68 + cg*4] = wv2;
            *(float4*)&w_t[(wr + 48)*68 + cg*4] = wv3;
        }
        __syncthreads();
        if (kk + KT < DMODEL) {   // prefetch next tile
            const float* xsrc = x + (size_t)(row0+xr)*DMODEL + (kk+KT) + xq*16;
            xv0 = *(const float4*)(xsrc);     xv1 = *(const float4*)(xsrc + 4);
            xv2 = *(const float4*)(xsrc + 8); xv3 = *(const float4*)(xsrc + 12);
            wv0 = *(const float4*)(wbase + (size_t)(kk+KT + wr     )*NPROJ);
            wv1 = *(const float4*)(wbase + (size_t)(kk+KT + wr + 16)*NPROJ);
            wv2 = *(const float4*)(wbase + (size_t)(kk+KT + wr + 32)*NPROJ);
            wv3 = *(const float4*)(wbase + (size_t)(kk+KT + wr + 48)*NPROJ);
        }
        #pragma unroll 4
        for (int k=0;k<KT;k++) {
            const float4 xf = *(const float4*)&x_t[k*68 + rg*4];
            const float4 wf = *(const float4*)&w_t[k*68 + cg*4];
            const double xd0=(double)xf.x, xd1=(double)xf.y, xd2=(double)xf.z, xd3=(double)xf.w;
            const double wd0=(double)wf.x, wd1=(double)wf.y, wd2=(double)wf.z, wd3=(double)wf.w;
            PJROW(0) PJROW(1) PJROW(2) PJROW(3)
        }
    }

    float*  hhi = out + obase;                       // [64][64] f32
    ushort* hlo = (ushort*)(out + obase + 4096);     // [64][64] bf16
    const double bj0=(double)bb[head*64+cg*4+0], bj1=(double)bb[head*64+cg*4+1];
    const double bj2=(double)bb[head*64+cg*4+2], bj3=(double)bb[head*64+cg*4+3];
    EPI(0) EPI(1) EPI(2) EPI(3)
}

// ======================= Kernel 2: router =======================
__global__ __launch_bounds__(256, 3)
void route_k(const float* __restrict__ emb, const ushort* __restrict__ ebf,
             float* __restrict__ out)
{
    __shared__ int    ridx16[64*16];                 // 4096 B
    __shared__ float  zbuf[64];
    __shared__ double rv[64*17];                     // 8704 B
    __shared__ __align__(8) float final8[64*16];     // 4096 B

    const int t    = threadIdx.x;
    const int lane = t & 63, wv = t >> 6;
    const int m    = lane & 15, q = lane >> 4;
    const int head = blockIdx.y;
    const int row0 = blockIdx.x * TILE_M;
    const size_t obase = ((size_t)head*NROWS + row0) * (size_t)NPOOL;

    int psel = 0;                 // pools: [fqk,fqk,fv,rqk,rqk,rv]
    if (head >= 2) psel = 1;
    if (head >= 3) psel = 2;
    if (head >= 5) psel = 3;
    const float*  epool = emb + (size_t)psel * NPOOL * DSP;
    const ushort* ebase = ebf + (size_t)psel * NPOOL * DSP;

    // ---- A fragments: h rows of this wave, bf16, from h_hi scratch ----
    union FragU { unsigned int u[4]; short8 s; };
    FragU A0, A1;
    {
        const float* hr = out + obase + (size_t)(wv*16 + m)*64 + q*8;
        const float4 a0 = *(const float4*)(hr);
        const float4 a1 = *(const float4*)(hr + 4);
        const float4 a2 = *(const float4*)(hr + 32);
        const float4 a3 = *(const float4*)(hr + 36);
        A0.u[0]=packbf2(a0.x,a0.y); A0.u[1]=packbf2(a0.z,a0.w);
        A0.u[2]=packbf2(a1.x,a1.y); A0.u[3]=packbf2(a1.z,a1.w);
        A1.u[0]=packbf2(a2.x,a2.y); A1.u[1]=packbf2(a2.z,a2.w);
        A1.u[2]=packbf2(a3.x,a3.y); A1.u[3]=packbf2(a3.z,a3.w);
    }

    // ---- Phase 1: MFMA logits, Z, per-lane top-8; B-frags = prepacked bf16 ----
    DECL8(0) DECL8(1) DECL8(2) DECL8(3)
    float zacc0=0.f, zacc1=0.f, zacc2=0.f, zacc3=0.f;

    #pragma unroll 1
    for (int it=0; it<128; ++it) {
        const int cidx = it*16 + m;                 // e row this lane needs
        const ushort* ep = ebase + (size_t)cidx*DSP + q*8;
        const short8 B0 = *(const short8*)(ep);
        const short8 B1 = *(const short8*)(ep + 32);

        f32x4 cc = {0.f,0.f,0.f,0.f};
        cc = __builtin_amdgcn_mfma_f32_16x16x32_bf16(A0.s, B0, cc, 0, 0, 0);
        cc = __builtin_amdgcn_mfma_f32_16x16x32_bf16(A1.s, B1, cc, 0, 0, 0);

        { const float w_ = cc[0]; zacc0 += exp2f(w_ - C2); INS8(0, w_, cidx) }
        { const float w_ = cc[1]; zacc1 += exp2f(w_ - C2); INS8(1, w_, cidx) }
        { const float w_ = cc[2]; zacc2 += exp2f(w_ - C2); INS8(2, w_, cidx) }
        { const float w_ = cc[3]; zacc3 += exp2f(w_ - C2); INS8(3, w_, cidx) }
    }

    // ---- Z reduce over the 16 col-lanes of each row ----
    { float z=zacc0; z+=__shfl_xor(z,1,64); z+=__shfl_xor(z,2,64); z+=__shfl_xor(z,4,64); z+=__shfl_xor(z,8,64); if(m==0) zbuf[wv*16+q*4+0]=z; }
    { float z=zacc1; z+=__shfl_xor(z,1,64); z+=__shfl_xor(z,2,64); z+=__shfl_xor(z,4,64); z+=__shfl_xor(z,8,64); if(m==0) zbuf[wv*16+q*4+1]=z; }
    { float z=zacc2; z+=__shfl_xor(z,1,64); z+=__shfl_xor(z,2,64); z+=__shfl_xor(z,4,64); z+=__shfl_xor(z,8,64); if(m==0) zbuf[wv*16+q*4+2]=z; }
    { float z=zacc3; z+=__shfl_xor(z,1,64); z+=__shfl_xor(z,2,64); z+=__shfl_xor(z,4,64); z+=__shfl_xor(z,8,64); if(m==0) zbuf[wv*16+q*4+3]=z; }

    // ---- in-wave tournament: per-row top-16 into ridx16 (sorted desc) ----
    TOURN(0, wv*16 + q*4 + 0)
    TOURN(1, wv*16 + q*4 + 1)
    TOURN(2, wv*16 + q*4 + 2)
    TOURN(3, wv*16 + q*4 + 3)
    __syncthreads();

    // ---- Phase 3: fp64 rescore of the 16 candidates per row ----
    {
        const int row = t >> 2, q4 = t & 3;   // 4 candidates per thread
        const int ix0 = ridx16[row*16 + q4*4 + 0];
        const int ix1 = ridx16[row*16 + q4*4 + 1];
        const int ix2 = ridx16[row*16 + q4*4 + 2];
        const int ix3 = ridx16[row*16 + q4*4 + 3];
        const float* ep0 = epool + (size_t)ix0*DSP;
        const float* ep1 = epool + (size_t)ix1*DSP;
        const float* ep2 = epool + (size_t)ix2*DSP;
        const float* ep3 = epool + (size_t)ix3*DSP;
        const float*  hhr = out + obase + (size_t)row*64;
        const ushort* hlr = (const ushort*)(out + obase + 4096) + (size_t)row*64;
        double nn0=0,nn1=0,nn2=0,nn3=0, dd0=0,dd1=0,dd2=0,dd3=0;
        #pragma unroll 1
        for (int k4=0; k4<DSP; k4+=4) {
            const double h0 = (double)hhr[k4+0] + (double)bf2f(hlr[k4+0]);
            const double h1 = (double)hhr[k4+1] + (double)bf2f(hlr[k4+1]);
            const double h2 = (double)hhr[k4+2] + (double)bf2f(hlr[k4+2]);
            const double h3 = (double)hhr[k4+3] + (double)bf2f(hlr[k4+3]);
            #define RS(s) { const float4 e_ = *(const float4*)(ep##s + k4); \
                const double e0_=(double)e_.x, e1_=(double)e_.y, e2_=(double)e_.z, e3_=(double)e_.w; \
                nn##s += e0_*e0_ + e1_*e1_ + e2_*e2_ + e3_*e3_; \
                dd##s += h0*e0_ + h1*e1_ + h2*e2_ + h3*e3_; }
            RS(0) RS(1) RS(2) RS(3)
            #undef RS
        }
        rv[row*17 + q4*4 + 0] = dd0 / fmax(sqrt(nn0), 1e-12);
        rv[row*17 + q4*4 + 1] = dd1 / fmax(sqrt(nn1), 1e-12);
        rv[row*17 + q4*4 + 2] = dd2 / fmax(sqrt(nn2), 1e-12);
        rv[row*17 + q4*4 + 3] = dd3 / fmax(sqrt(nn3), 1e-12);
    }
    __syncthreads();

    // ---- Phase 4: fp64 top-8 select (named scalars), normalize, stash in LDS ----
    if (t < 64) {
        const float Zg = zbuf[t];
        double dv0=-INFINITY,dv1=-INFINITY,dv2=-INFINITY,dv3=-INFINITY,
               dv4=-INFINITY,dv5=-INFINITY,dv6=-INFINITY,dv7=-INFINITY;
        int    di0=IMAX,di1=IMAX,di2=IMAX,di3=IMAX,di4=IMAX,di5=IMAX,di6=IMAX,di7=IMAX;
        #pragma unroll 1
        for (int s=0;s<KEEP;s++) {
            const double v_  = rv[t*17 + s];
            const int    ix_ = ridx16[t*16 + s];
            INS8D(v_, ix_)
        }
        float denom = 1e-8f * Zg;
        const float ov0 = exp2f((float)(dv0*LOG2E_D) - C2); denom += ov0;
        const float ov1 = exp2f((float)(dv1*LOG2E_D) - C2); denom += ov1;
        const float ov2 = exp2f((float)(dv2*LOG2E_D) - C2); denom += ov2;
        const float ov3 = exp2f((float)(dv3*LOG2E_D) - C2); denom += ov3;
        const float ov4 = exp2f((float)(dv4*LOG2E_D) - C2); denom += ov4;
        const float ov5 = exp2f((float)(dv5*LOG2E_D) - C2); denom += ov5;
        const float ov6 = exp2f((float)(dv6*LOG2E_D) - C2); denom += ov6;
        const float ov7 = exp2f((float)(dv7*LOG2E_D) - C2); denom += ov7;
        const float rd = 1.0f / denom;
        float2 p;
        p.x=ov0*rd; p.y=__int_as_float(di0); *(float2*)&final8[t*16 +  0] = p;
        p.x=ov1*rd; p.y=__int_as_float(di1); *(float2*)&final8[t*16 +  2] = p;
        p.x=ov2*rd; p.y=__int_as_float(di2); *(float2*)&final8[t*16 +  4] = p;
        p.x=ov3*rd; p.y=__int_as_float(di3); *(float2*)&final8[t*16 +  6] = p;
        p.x=ov4*rd; p.y=__int_as_float(di4); *(float2*)&final8[t*16 +  8] = p;
        p.x=ov5*rd; p.y=__int_as_float(di5); *(float2*)&final8[t*16 + 10] = p;
        p.x=ov6*rd; p.y=__int_as_float(di6); *(float2*)&final8[t*16 + 12] = p;
        p.x=ov7*rd; p.y=__int_as_float(di7); *(float2*)&final8[t*16 + 14] = p;
    }
    __syncthreads();   // drains rescore loads + final8 stores before overwrite

    // ---- Phase 5: merged zero+scatter burst write (one visit per line) ----
    #pragma unroll 1
    for (int rr=0; rr<16; ++rr) {
        const int row = rr*4 + wv;          // one row per wave
        const float* fb = &final8[row*16];  // broadcast LDS reads
        const float pv0=fb[ 0]; const int pi0=__float_as_int(fb[ 1]);
        const float pv1=fb[ 2]; const int pi1=__float_as_int(fb[ 3]);
        const float pv2=fb[ 4]; const int pi2=__float_as_int(fb[ 5]);
        const float pv3=fb[ 6]; const int pi3=__float_as_int(fb[ 7]);
        const float pv4=fb[ 8]; const int pi4=__float_as_int(fb[ 9]);
        const float pv5=fb[10]; const int pi5=__float_as_int(fb[11]);
        const float pv6=fb[12]; const int pi6=__float_as_int(fb[13]);
        const float pv7=fb[14]; const int pi7=__float_as_int(fb[15]);
        float* orow = out + obase + (size_t)row*NPOOL;
        #pragma unroll
        for (int j=0;j<8;j++) {
            const int base4 = (j*64 + lane)*4;
            float v0=0.f, v1=0.f, v2=0.f, v3=0.f;
            #define SCAT(s) { const int d_ = pi##s - base4; \
                v0=(d_==0)?pv##s:v0; v1=(d_==1)?pv##s:v1; \
                v2=(d_==2)?pv##s:v2; v3=(d_==3)?pv##s:v3; }
            SCAT(0) SCAT(1) SCAT(2) SCAT(3) SCAT(4) SCAT(5) SCAT(6) SCAT(7)
            #undef SCAT
            *(float4*)&orow[base4] = make_float4(v0,v1,v2,v3);
        }
    }
}

extern "C" void kernel_launch(void* const* d_in, const int* in_sizes, int n_in,
                              void* d_out, int out_size, void* d_ws, size_t ws_size,
                              hipStream_t stream) {
    (void)in_sizes; (void)n_in; (void)ws_size; (void)out_size;
    const float* x   = (const float*)d_in[0];
    const float* Wm  = (const float*)d_in[1];
    const float* bb  = (const float*)d_in[2];
    const float* emb = (const float*)d_in[3];
    float*  out = (float*)d_out;
    ushort* ebf = (ushort*)d_ws;          // 4*2048*64 bf16 = 1 MB scratch
    dim3 grid(NROWS / TILE_M, HEADS);
    prep_k <<<32, 256, 0, stream>>>(emb, ebf);
    proj_k <<<grid, dim3(256), 0, stream>>>(x, Wm, bb, out);
    route_k<<<grid, dim3(256), 0, stream>>>(emb, ebf, out);
}